// Round 4
// baseline (245.355 us; speedup 1.0000x reference)
//
#include <hip/hip_runtime.h>

// ---------------- problem constants ----------------
#define BATCH 2
#define SEQ   2048
#define NH    16
#define DH    64
#define DA    128          // augmented head dim (content 64 + pos 64)
#define DM    1024
#define MTOT  (BATCH*SEQ)  // 4096

typedef _Float16 f16x8 __attribute__((ext_vector_type(8)));
typedef _Float16 f16x4 __attribute__((ext_vector_type(4)));
typedef float    f32x4 __attribute__((ext_vector_type(4)));

#define LOG2E 1.44269504088896340736f

// workspace offsets (bytes)
#define OFF_X16 0u
#define OFF_WQ  8388608u
#define OFF_WK  10485760u
#define OFF_WV  12582912u
#define OFF_WO  14680064u
#define OFF_QA  16777216u
#define OFF_KA  33554432u
#define OFF_VT  50331648u
#define OFF_AO  58720256u
// total 67108864 (64 MB)

__device__ __forceinline__ void gload_lds16(const _Float16* g, _Float16* l) {
  __builtin_amdgcn_global_load_lds(
      (const __attribute__((address_space(1))) unsigned int*)g,
      (__attribute__((address_space(3))) unsigned int*)l, 16, 0, 0);
}

// ---------------- fp32 -> fp16 conversion (x + 4 weights) ----------------
// dst regions are contiguous: x16 (4M halves) then Wq,Wk,Wv,Wo (1M halves each)
__global__ __launch_bounds__(256) void cvt_all(
    const float* __restrict__ x,  const float* __restrict__ wq,
    const float* __restrict__ wk, const float* __restrict__ wv,
    const float* __restrict__ wo, _Float16* __restrict__ dst)
{
  int i = blockIdx.x * 256 + threadIdx.x;   // each thread: 8 floats
  const float* src;
  if (i < 524288) {
    src = x + (size_t)i * 8;
  } else {
    int j = i - 524288;
    int wi = j >> 17;                        // 131072 threads per weight
    const float* w = (wi == 0) ? wq : ((wi == 1) ? wk : ((wi == 2) ? wv : wo));
    src = w + (size_t)(j & 131071) * 8;
  }
  float4 a = ((const float4*)src)[0];
  float4 c = ((const float4*)src)[1];
  f16x8 hv;
  hv[0]=(_Float16)a.x; hv[1]=(_Float16)a.y; hv[2]=(_Float16)a.z; hv[3]=(_Float16)a.w;
  hv[4]=(_Float16)c.x; hv[5]=(_Float16)c.y; hv[6]=(_Float16)c.z; hv[7]=(_Float16)c.w;
  *(f16x8*)(dst + (size_t)i * 8) = hv;
}

// ---------------- fill positional halves of Qa/Ka ----------------
// Qa[b,h,s,64+d] = alpha[h]*pe[s,d] ; Ka[b,h,s,64+d] = pe[s,d]
__global__ __launch_bounds__(256) void fill_pe(
    const float* __restrict__ pe, const float* __restrict__ alpha,
    _Float16* __restrict__ Qa, _Float16* __restrict__ Ka)
{
  int idx = blockIdx.x * 256 + threadIdx.x;   // B*H*S*64 = 2^22 threads
  int d = idx & 63;
  int s = (idx >> 6) & 2047;
  int h = (idx >> 17) & 15;
  int b = idx >> 21;
  float p = pe[s * 64 + d];
  size_t o = ((size_t)((b * NH + h) * SEQ + s)) * DA + 64 + d;
  Qa[o] = (_Float16)(alpha[h] * p);
  Ka[o] = (_Float16)p;
}

// ---------------- NT GEMM: C(M x N) = A(M x K) * W(N x K)^T ----------------
// MODE 0: fused QKV (grid.x = 24 : 8 n-blocks per matrix), epilogue scatters
//         into per-head Qa (scaled 1/8), Ka, and V transposed (Vt[bh,d,s]).
// MODE 1: output projection, epilogue writes fp32 d_out + bias.
// 128x128 tile, BK=64, 4 waves (each 64x64), global_load_lds w=16,
// LDS XOR-swizzled: LDS[row][c] = G[row][c ^ (row&7)] (16B chunks).
template<int MODE>
__global__ __launch_bounds__(256) void gemm_nt(
    const _Float16* __restrict__ A,
    const _Float16* __restrict__ W0, const _Float16* __restrict__ W1,
    const _Float16* __restrict__ W2,
    const float* __restrict__ b0, const float* __restrict__ b1,
    const float* __restrict__ b2,
    _Float16* __restrict__ Qa, _Float16* __restrict__ Ka,
    _Float16* __restrict__ Vt, float* __restrict__ Out)
{
  __shared__ _Float16 As[128 * 64];
  __shared__ _Float16 Bs[128 * 64];
  const int tid = threadIdx.x;
  const int w = tid >> 6, lane = tid & 63;
  const int g = lane >> 4, l16 = lane & 15;
  const int wm = w >> 1, wn = w & 1;

  int nb_all = blockIdx.x;
  int mblk = blockIdx.y;
  const _Float16* Bp; const float* biasp;
  int which = 0, nblk = nb_all;
  if (MODE == 0) {
    which = nb_all >> 3; nblk = nb_all & 7;
    Bp = (which == 0) ? W0 : ((which == 1) ? W1 : W2);
    biasp = (which == 0) ? b0 : ((which == 1) ? b1 : b2);
  } else {
    Bp = W0; biasp = b0;
  }

  f32x4 zero4 = {0.f, 0.f, 0.f, 0.f};
  f32x4 acc[4][4];
  #pragma unroll
  for (int mb = 0; mb < 4; ++mb)
    #pragma unroll
    for (int nb = 0; nb < 4; ++nb) acc[mb][nb] = zero4;

  const _Float16* Abase = A  + (size_t)mblk * 128 * DM;
  const _Float16* Bbase = Bp + (size_t)nblk * 128 * DM;

  for (int kt = 0; kt < DM / 64; ++kt) {
    __syncthreads();
    #pragma unroll
    for (int ii = 0; ii < 4; ++ii) {              // stage A: 16 insts total
      int i = w * 4 + ii;
      int rt = i * 8 + (lane >> 3);
      int cg = (lane & 7) ^ (rt & 7);
      gload_lds16(Abase + (size_t)rt * DM + kt * 64 + cg * 8, &As[i * 512]);
    }
    #pragma unroll
    for (int ii = 0; ii < 4; ++ii) {              // stage B
      int i = w * 4 + ii;
      int rt = i * 8 + (lane >> 3);
      int cg = (lane & 7) ^ (rt & 7);
      gload_lds16(Bbase + (size_t)rt * DM + kt * 64 + cg * 8, &Bs[i * 512]);
    }
    __syncthreads();
    #pragma unroll
    for (int ks = 0; ks < 2; ++ks) {
      f16x8 av[4], bv[4];
      #pragma unroll
      for (int mb = 0; mb < 4; ++mb) {
        int rt = wm * 64 + mb * 16 + l16;
        av[mb] = *(const f16x8*)&As[rt * 64 + (((ks * 4 + g) ^ (rt & 7)) * 8)];
      }
      #pragma unroll
      for (int nb = 0; nb < 4; ++nb) {
        int rt = wn * 64 + nb * 16 + l16;
        bv[nb] = *(const f16x8*)&Bs[rt * 64 + (((ks * 4 + g) ^ (rt & 7)) * 8)];
      }
      #pragma unroll
      for (int mb = 0; mb < 4; ++mb)
        #pragma unroll
        for (int nb = 0; nb < 4; ++nb)
          acc[mb][nb] = __builtin_amdgcn_mfma_f32_16x16x32_f16(
              av[mb], bv[nb], acc[mb][nb], 0, 0, 0);
    }
  }

  // epilogue
  #pragma unroll
  for (int nb = 0; nb < 4; ++nb) {
    int n = nblk * 128 + wn * 64 + nb * 16 + l16;   // 0..1023 in selected W
    float bias = biasp[n];
    #pragma unroll
    for (int mb = 0; mb < 4; ++mb) {
      int m0 = mblk * 128 + wm * 64 + mb * 16 + g * 4;
      if (MODE == 0) {
        int hh = n >> 6, dd = n & 63;
        if (which == 2) {                    // V: write transposed Vt[bh,d,s]
          int bb = m0 >> 11, ss = m0 & 2047;
          f16x4 hv;
          #pragma unroll
          for (int r = 0; r < 4; ++r) hv[r] = (_Float16)(acc[mb][nb][r] + bias);
          *(f16x4*)&Vt[((size_t)((bb * NH + hh) * DH + dd)) * SEQ + ss] = hv;
        } else {
          #pragma unroll
          for (int r = 0; r < 4; ++r) {
            int m = m0 + r; int bb = m >> 11, ss = m & 2047;
            size_t o = ((size_t)((bb * NH + hh) * SEQ + ss)) * DA + dd;
            if (which == 0) Qa[o] = (_Float16)((acc[mb][nb][r] + bias) * 0.125f);
            else            Ka[o] = (_Float16)(acc[mb][nb][r] + bias);
          }
        }
      } else {
        #pragma unroll
        for (int r = 0; r < 4; ++r)
          Out[(size_t)(m0 + r) * DM + n] = acc[mb][nb][r] + bias;
      }
    }
  }
}

// ---------------- flash attention ----------------
// grid: B*H*(S/128) = 512 blocks; 4 waves, wave = 32 q-rows.
// Qa/Ka have Da=128 (content/8 | pos), Vt is [bh][d][s].
__global__ __launch_bounds__(256) void flash_attn(
    const _Float16* __restrict__ Qa, const _Float16* __restrict__ Ka,
    const _Float16* __restrict__ Vt, const int* __restrict__ mask,
    _Float16* __restrict__ AO)
{
  __shared__ _Float16 Ks[64 * 128];   // K-tile  [key][Da]   (swizzled)
  __shared__ _Float16 Vs[64 * 64];    // Vt-tile [d][key]    (swizzled)
  __shared__ _Float16 Ps[128 * 64];   // P       [q][key]    (wave-private rows)
  const int tid = threadIdx.x;
  const int w = tid >> 6, lane = tid & 63;
  const int g = lane >> 4, l16 = lane & 15;
  const int qt = blockIdx.x & 15;
  const int h  = (blockIdx.x >> 4) & 15;
  const int b  = blockIdx.x >> 8;

  const _Float16* qbase = Qa + ((size_t)((b * NH + h) * SEQ) + qt * 128 + w * 32) * DA;
  f16x8 qf[2][4];
  #pragma unroll
  for (int mb = 0; mb < 2; ++mb)
    #pragma unroll
    for (int ks = 0; ks < 4; ++ks)
      qf[mb][ks] = *(const f16x8*)&qbase[(mb * 16 + l16) * DA + ks * 32 + g * 8];

  f32x4 zero4 = {0.f, 0.f, 0.f, 0.f};
  f32x4 acco[2][4];
  float mrun[2][4], lrun[2][4];
  #pragma unroll
  for (int mb = 0; mb < 2; ++mb) {
    #pragma unroll
    for (int nd = 0; nd < 4; ++nd) acco[mb][nd] = zero4;
    #pragma unroll
    for (int r = 0; r < 4; ++r) { mrun[mb][r] = -3.0e38f; lrun[mb][r] = 0.f; }
  }

  const _Float16* kbase = Ka + ((size_t)((b * NH + h) * SEQ)) * DA;
  const _Float16* vbase = Vt + ((size_t)((b * NH + h) * DH)) * SEQ;
  const int* mbase = mask + b * SEQ;
  _Float16* pbase = &Ps[w * 32 * 64];

  for (int kt = 0; kt < SEQ / 64; ++kt) {
    __syncthreads();
    #pragma unroll
    for (int ii = 0; ii < 4; ++ii) {            // stage K: 16 insts (4/wave)
      int i = w * 4 + ii;
      int rt = i * 4 + (lane >> 4);
      int cg = (lane & 15) ^ (rt & 7);
      gload_lds16(kbase + (size_t)(kt * 64 + rt) * DA + cg * 8, &Ks[i * 512]);
    }
    #pragma unroll
    for (int ii = 0; ii < 2; ++ii) {            // stage Vt: 8 insts (2/wave)
      int i = w * 2 + ii;
      int rt = i * 8 + (lane >> 3);
      int cg = (lane & 7) ^ (rt & 7);
      gload_lds16(vbase + (size_t)rt * SEQ + kt * 64 + cg * 8, &Vs[i * 512]);
    }
    __syncthreads();

    // S = Qa @ Ka^T  (32q x 64k per wave)
    f32x4 sfr[2][4];
    #pragma unroll
    for (int nb = 0; nb < 4; ++nb) {
      f16x8 kf[4];
      int rt = nb * 16 + l16;
      #pragma unroll
      for (int ks = 0; ks < 4; ++ks)
        kf[ks] = *(const f16x8*)&Ks[rt * 128 + (((ks * 4 + g) ^ (rt & 7)) * 8)];
      #pragma unroll
      for (int mb = 0; mb < 2; ++mb) {
        f32x4 s = zero4;
        #pragma unroll
        for (int ks = 0; ks < 4; ++ks)
          s = __builtin_amdgcn_mfma_f32_16x16x32_f16(qf[mb][ks], kf[ks], s, 0, 0, 0);
        sfr[mb][nb] = s;
      }
    }
    // mask (all-ones in practice; keep for correctness)
    #pragma unroll
    for (int nb = 0; nb < 4; ++nb) {
      if (mbase[kt * 64 + nb * 16 + l16] == 0) {
        #pragma unroll
        for (int mb = 0; mb < 2; ++mb)
          #pragma unroll
          for (int r = 0; r < 4; ++r) sfr[mb][nb][r] = -3.0e38f;
      }
    }
    // online softmax (row = q; cols spread over nb regs x l16 lanes)
    #pragma unroll
    for (int mb = 0; mb < 2; ++mb) {
      #pragma unroll
      for (int r = 0; r < 4; ++r) {
        float mx = fmaxf(fmaxf(sfr[mb][0][r], sfr[mb][1][r]),
                         fmaxf(sfr[mb][2][r], sfr[mb][3][r]));
        mx = fmaxf(mx, __shfl_xor(mx, 1));
        mx = fmaxf(mx, __shfl_xor(mx, 2));
        mx = fmaxf(mx, __shfl_xor(mx, 4));
        mx = fmaxf(mx, __shfl_xor(mx, 8));
        float mnew = fmaxf(mrun[mb][r], mx);
        float scale = exp2f((mrun[mb][r] - mnew) * LOG2E);
        float rsum = 0.f;
        #pragma unroll
        for (int nb = 0; nb < 4; ++nb) {
          float p = exp2f((sfr[mb][nb][r] - mnew) * LOG2E);
          sfr[mb][nb][r] = p;
          rsum += p;
        }
        rsum += __shfl_xor(rsum, 1);
        rsum += __shfl_xor(rsum, 2);
        rsum += __shfl_xor(rsum, 4);
        rsum += __shfl_xor(rsum, 8);
        lrun[mb][r] = lrun[mb][r] * scale + rsum;
        mrun[mb][r] = mnew;
        #pragma unroll
        for (int nd = 0; nd < 4; ++nd) acco[mb][nd][r] *= scale;
      }
    }
    // P -> wave-private LDS (swizzled), converting to f16
    #pragma unroll
    for (int mb = 0; mb < 2; ++mb)
      #pragma unroll
      for (int r = 0; r < 4; ++r) {
        int row = mb * 16 + g * 4 + r;
        int sw = (row & 7) << 3;
        #pragma unroll
        for (int nb = 0; nb < 4; ++nb)
          pbase[row * 64 + ((nb * 16 + l16) ^ sw)] = (_Float16)sfr[mb][nb][r];
      }
    // O += P @ V   (reduction over 64 keys = 2 MFMA k-steps)
    #pragma unroll
    for (int ks2 = 0; ks2 < 2; ++ks2) {
      f16x8 pf[2];
      #pragma unroll
      for (int mb = 0; mb < 2; ++mb) {
        int row = mb * 16 + l16;
        pf[mb] = *(const f16x8*)&pbase[row * 64 + (((ks2 * 4 + g) ^ (row & 7)) * 8)];
      }
      #pragma unroll
      for (int nd = 0; nd < 4; ++nd) {
        int row = nd * 16 + l16;
        f16x8 vf = *(const f16x8*)&Vs[row * 64 + (((ks2 * 4 + g) ^ (row & 7)) * 8)];
        #pragma unroll
        for (int mb = 0; mb < 2; ++mb)
          acco[mb][nd] = __builtin_amdgcn_mfma_f32_16x16x32_f16(
              pf[mb], vf, acco[mb][nd], 0, 0, 0);
      }
    }
  }

  // epilogue: AO[b,s,h*64+d] = acco / l
  #pragma unroll
  for (int mb = 0; mb < 2; ++mb) {
    #pragma unroll
    for (int r = 0; r < 4; ++r) {
      float inv = 1.0f / lrun[mb][r];
      int sg = qt * 128 + w * 32 + mb * 16 + g * 4 + r;
      #pragma unroll
      for (int nd = 0; nd < 4; ++nd) {
        int col = h * DH + nd * 16 + l16;
        AO[((size_t)(b * SEQ + sg)) * DM + col] = (_Float16)(acco[mb][nd][r] * inv);
      }
    }
  }
}

// ---------------- launch ----------------
extern "C" void kernel_launch(void* const* d_in, const int* in_sizes, int n_in,
                              void* d_out, int out_size, void* d_ws, size_t ws_size,
                              hipStream_t stream) {
  const float* x     = (const float*)d_in[0];
  const int*   mask  = (const int*)  d_in[1];
  const float* Wq    = (const float*)d_in[2];
  const float* bq    = (const float*)d_in[3];
  const float* Wk    = (const float*)d_in[4];
  const float* bk    = (const float*)d_in[5];
  const float* Wv    = (const float*)d_in[6];
  const float* bv    = (const float*)d_in[7];
  const float* Wo    = (const float*)d_in[8];
  const float* bo    = (const float*)d_in[9];
  const float* pe    = (const float*)d_in[10];
  const float* alpha = (const float*)d_in[11];
  // beta (d_in[12]) is softmax-invariant (uniform per row) -> unused

  char* ws = (char*)d_ws;
  _Float16* x16 = (_Float16*)(ws + OFF_X16);
  _Float16* wq6 = (_Float16*)(ws + OFF_WQ);
  _Float16* wk6 = (_Float16*)(ws + OFF_WK);
  _Float16* wv6 = (_Float16*)(ws + OFF_WV);
  _Float16* wo6 = (_Float16*)(ws + OFF_WO);
  _Float16* Qa  = (_Float16*)(ws + OFF_QA);
  _Float16* Ka  = (_Float16*)(ws + OFF_KA);
  _Float16* Vt  = (_Float16*)(ws + OFF_VT);
  _Float16* AO  = (_Float16*)(ws + OFF_AO);
  float* out = (float*)d_out;

  cvt_all<<<4096, 256, 0, stream>>>(x, Wq, Wk, Wv, Wo, x16);
  fill_pe<<<16384, 256, 0, stream>>>(pe, alpha, Qa, Ka);
  gemm_nt<0><<<dim3(24, 32), 256, 0, stream>>>(x16, wq6, wk6, wv6, bq, bk, bv,
                                               Qa, Ka, Vt, nullptr);
  flash_attn<<<512, 256, 0, stream>>>(Qa, Ka, Vt, mask, AO);
  gemm_nt<1><<<dim3(8, 32), 256, 0, stream>>>(AO, wo6, nullptr, nullptr, bo,
                                              nullptr, nullptr, nullptr, nullptr,
                                              nullptr, out);
}

// Round 5
// 229.132 us; speedup vs baseline: 1.0708x; 1.0708x over previous
//
#include <hip/hip_runtime.h>

// ---------------- problem constants ----------------
#define BATCH 2
#define SEQ   2048
#define NH    16
#define DH    64
#define DA    128          // augmented head dim (content 64 + pos 64)
#define DM    1024
#define MTOT  (BATCH*SEQ)  // 4096

typedef _Float16 f16x8 __attribute__((ext_vector_type(8)));
typedef _Float16 f16x4 __attribute__((ext_vector_type(4)));
typedef float    f32x4 __attribute__((ext_vector_type(4)));

#define LOG2E 1.44269504088896340736f

// workspace offsets (bytes)
#define OFF_X16 0u
#define OFF_WQ  8388608u
#define OFF_WK  10485760u
#define OFF_WV  12582912u
#define OFF_WO  14680064u
#define OFF_QA  16777216u
#define OFF_KA  33554432u
#define OFF_VT  50331648u
#define OFF_AO  58720256u
// total 67108864 (64 MB)

__device__ __forceinline__ void gload_lds16(const _Float16* g, _Float16* l) {
  __builtin_amdgcn_global_load_lds(
      (const __attribute__((address_space(1))) unsigned int*)g,
      (__attribute__((address_space(3))) unsigned int*)l, 16, 0, 0);
}

// ---------------- fp32 -> fp16 conversion (x + 4 weights) ----------------
__global__ __launch_bounds__(256) void cvt_all(
    const float* __restrict__ x,  const float* __restrict__ wq,
    const float* __restrict__ wk, const float* __restrict__ wv,
    const float* __restrict__ wo, _Float16* __restrict__ dst)
{
  int i = blockIdx.x * 256 + threadIdx.x;   // each thread: 8 floats
  const float* src;
  if (i < 524288) {
    src = x + (size_t)i * 8;
  } else {
    int j = i - 524288;
    int wi = j >> 17;                        // 131072 threads per weight
    const float* w = (wi == 0) ? wq : ((wi == 1) ? wk : ((wi == 2) ? wv : wo));
    src = w + (size_t)(j & 131071) * 8;
  }
  float4 a = ((const float4*)src)[0];
  float4 c = ((const float4*)src)[1];
  f16x8 hv;
  hv[0]=(_Float16)a.x; hv[1]=(_Float16)a.y; hv[2]=(_Float16)a.z; hv[3]=(_Float16)a.w;
  hv[4]=(_Float16)c.x; hv[5]=(_Float16)c.y; hv[6]=(_Float16)c.z; hv[7]=(_Float16)c.w;
  *(f16x8*)(dst + (size_t)i * 8) = hv;
}

// ---------------- fill positional halves of Qa/Ka (8-wide vectorized) -------
// Qa[b,h,s,64+d] = alpha[h]*pe[s,d] ; Ka[b,h,s,64+d] = pe[s,d]
__global__ __launch_bounds__(256) void fill_pe(
    const float* __restrict__ pe, const float* __restrict__ alpha,
    _Float16* __restrict__ Qa, _Float16* __restrict__ Ka)
{
  int idx = blockIdx.x * 256 + threadIdx.x;   // B*H*S*8 = 2^19 threads
  int c8 = idx & 7;            // which 8-chunk of the 64 pos dims
  int s  = (idx >> 3) & 2047;
  int h  = (idx >> 14) & 15;
  int b  = idx >> 18;
  const float4* p4 = (const float4*)(pe + s * 64 + c8 * 8);
  float4 a = p4[0], c = p4[1];
  float al = alpha[h];
  f16x8 hk, hq;
  hk[0]=(_Float16)a.x; hk[1]=(_Float16)a.y; hk[2]=(_Float16)a.z; hk[3]=(_Float16)a.w;
  hk[4]=(_Float16)c.x; hk[5]=(_Float16)c.y; hk[6]=(_Float16)c.z; hk[7]=(_Float16)c.w;
  hq[0]=(_Float16)(al*a.x); hq[1]=(_Float16)(al*a.y); hq[2]=(_Float16)(al*a.z); hq[3]=(_Float16)(al*a.w);
  hq[4]=(_Float16)(al*c.x); hq[5]=(_Float16)(al*c.y); hq[6]=(_Float16)(al*c.z); hq[7]=(_Float16)(al*c.w);
  size_t o = ((size_t)((b * NH + h) * SEQ + s)) * DA + 64 + c8 * 8;
  *(f16x8*)&Qa[o] = hq;
  *(f16x8*)&Ka[o] = hk;
}

// ---------------- NT GEMM: C(M x N) = A(M x K) * W(N x K)^T ----------------
// MODE 0: fused QKV (grid.x = 24 : 8 n-blocks per matrix), epilogue scatters
//         into per-head Qa (scaled 1/8), Ka, and V transposed (Vt[bh,d,s]).
// MODE 1: output projection, epilogue writes fp32 d_out + bias.
template<int MODE>
__global__ __launch_bounds__(256) void gemm_nt(
    const _Float16* __restrict__ A,
    const _Float16* __restrict__ W0, const _Float16* __restrict__ W1,
    const _Float16* __restrict__ W2,
    const float* __restrict__ b0, const float* __restrict__ b1,
    const float* __restrict__ b2,
    _Float16* __restrict__ Qa, _Float16* __restrict__ Ka,
    _Float16* __restrict__ Vt, float* __restrict__ Out)
{
  __shared__ _Float16 As[128 * 64];
  __shared__ _Float16 Bs[128 * 64];
  const int tid = threadIdx.x;
  const int w = tid >> 6, lane = tid & 63;
  const int g = lane >> 4, l16 = lane & 15;
  const int wm = w >> 1, wn = w & 1;

  int nb_all = blockIdx.x;
  int mblk = blockIdx.y;
  const _Float16* Bp; const float* biasp;
  int which = 0, nblk = nb_all;
  if (MODE == 0) {
    which = nb_all >> 3; nblk = nb_all & 7;
    Bp = (which == 0) ? W0 : ((which == 1) ? W1 : W2);
    biasp = (which == 0) ? b0 : ((which == 1) ? b1 : b2);
  } else {
    Bp = W0; biasp = b0;
  }

  f32x4 zero4 = {0.f, 0.f, 0.f, 0.f};
  f32x4 acc[4][4];
  #pragma unroll
  for (int mb = 0; mb < 4; ++mb)
    #pragma unroll
    for (int nb = 0; nb < 4; ++nb) acc[mb][nb] = zero4;

  const _Float16* Abase = A  + (size_t)mblk * 128 * DM;
  const _Float16* Bbase = Bp + (size_t)nblk * 128 * DM;

  for (int kt = 0; kt < DM / 64; ++kt) {
    __syncthreads();
    #pragma unroll
    for (int ii = 0; ii < 4; ++ii) {              // stage A: 16 insts total
      int i = w * 4 + ii;
      int rt = i * 8 + (lane >> 3);
      int cg = (lane & 7) ^ (rt & 7);
      gload_lds16(Abase + (size_t)rt * DM + kt * 64 + cg * 8, &As[i * 512]);
    }
    #pragma unroll
    for (int ii = 0; ii < 4; ++ii) {              // stage B
      int i = w * 4 + ii;
      int rt = i * 8 + (lane >> 3);
      int cg = (lane & 7) ^ (rt & 7);
      gload_lds16(Bbase + (size_t)rt * DM + kt * 64 + cg * 8, &Bs[i * 512]);
    }
    __syncthreads();
    #pragma unroll
    for (int ks = 0; ks < 2; ++ks) {
      f16x8 av[4], bv[4];
      #pragma unroll
      for (int mb = 0; mb < 4; ++mb) {
        int rt = wm * 64 + mb * 16 + l16;
        av[mb] = *(const f16x8*)&As[rt * 64 + (((ks * 4 + g) ^ (rt & 7)) * 8)];
      }
      #pragma unroll
      for (int nb = 0; nb < 4; ++nb) {
        int rt = wn * 64 + nb * 16 + l16;
        bv[nb] = *(const f16x8*)&Bs[rt * 64 + (((ks * 4 + g) ^ (rt & 7)) * 8)];
      }
      #pragma unroll
      for (int mb = 0; mb < 4; ++mb)
        #pragma unroll
        for (int nb = 0; nb < 4; ++nb)
          acc[mb][nb] = __builtin_amdgcn_mfma_f32_16x16x32_f16(
              av[mb], bv[nb], acc[mb][nb], 0, 0, 0);
    }
  }

  // epilogue
  #pragma unroll
  for (int nb = 0; nb < 4; ++nb) {
    int n = nblk * 128 + wn * 64 + nb * 16 + l16;   // 0..1023 in selected W
    float bias = biasp[n];
    #pragma unroll
    for (int mb = 0; mb < 4; ++mb) {
      int m0 = mblk * 128 + wm * 64 + mb * 16 + g * 4;
      if (MODE == 0) {
        int hh = n >> 6, dd = n & 63;
        if (which == 2) {                    // V: write transposed Vt[bh,d,s]
          int bb = m0 >> 11, ss = m0 & 2047;
          f16x4 hv;
          #pragma unroll
          for (int r = 0; r < 4; ++r) hv[r] = (_Float16)(acc[mb][nb][r] + bias);
          *(f16x4*)&Vt[((size_t)((bb * NH + hh) * DH + dd)) * SEQ + ss] = hv;
        } else {
          #pragma unroll
          for (int r = 0; r < 4; ++r) {
            int m = m0 + r; int bb = m >> 11, ss = m & 2047;
            size_t o = ((size_t)((bb * NH + hh) * SEQ + ss)) * DA + dd;
            if (which == 0) Qa[o] = (_Float16)((acc[mb][nb][r] + bias) * 0.125f);
            else            Ka[o] = (_Float16)(acc[mb][nb][r] + bias);
          }
        }
      } else {
        #pragma unroll
        for (int r = 0; r < 4; ++r)
          Out[(size_t)(m0 + r) * DM + n] = acc[mb][nb][r] + bias;
      }
    }
  }
}

// ---------------- flash attention ----------------
// grid: 1024 blocks (XCD-pinned swizzle); 4 waves, wave = 16 q-rows (QBLK=64).
// Qa/Ka have Da=128 (content/8 | pos), Vt is [bh][d][s].
__global__ __launch_bounds__(256, 4) void flash_attn(
    const _Float16* __restrict__ Qa, const _Float16* __restrict__ Ka,
    const _Float16* __restrict__ Vt, const int* __restrict__ mask,
    _Float16* __restrict__ AO)
{
  __shared__ _Float16 Ks[64 * 128];   // K-tile  [key][Da]   (swizzled) 16KB
  __shared__ _Float16 Vs[64 * 64];    // Vt-tile [d][key]    (swizzled)  8KB
  __shared__ _Float16 Ps[64 * 64];    // P       [q][key] (wave-private) 8KB
  const int tid = threadIdx.x;
  const int w = tid >> 6, lane = tid & 63;
  const int g = lane >> 4, l16 = lane & 15;

  // XCD-pinned swizzle: bid%8 = XCD (1024 blocks, 128/XCD). Each XCD owns
  // 4 whole (b,h) pairs -> K/V footprint 3MB < 4MB L2.
  int bid = blockIdx.x;
  int work = (bid & 7) * 128 + (bid >> 3);
  const int qt = work & 31;           // 32 q-tiles of 64 rows
  const int bh = work >> 5;           // 0..31
  const int h = bh & 15, b = bh >> 4;

  const _Float16* qbase = Qa + ((size_t)(bh * SEQ) + qt * 64 + w * 16) * DA;
  f16x8 qf[4];
  #pragma unroll
  for (int ks = 0; ks < 4; ++ks)
    qf[ks] = *(const f16x8*)&qbase[l16 * DA + ks * 32 + g * 8];

  f32x4 zero4 = {0.f, 0.f, 0.f, 0.f};
  f32x4 acco[4];
  float mrun[4], lrun[4];
  #pragma unroll
  for (int nd = 0; nd < 4; ++nd) acco[nd] = zero4;
  #pragma unroll
  for (int r = 0; r < 4; ++r) { mrun[r] = -3.0e38f; lrun[r] = 0.f; }

  const _Float16* kbase = Ka + (size_t)bh * SEQ * DA;
  const _Float16* vbase = Vt + (size_t)bh * DH * SEQ;
  const int* mbase = mask + b * SEQ;
  _Float16* pbase = &Ps[w * 16 * 64];

  for (int kt = 0; kt < SEQ / 64; ++kt) {
    __syncthreads();
    #pragma unroll
    for (int ii = 0; ii < 4; ++ii) {            // stage K: 16 insts (4/wave)
      int i = w * 4 + ii;
      int rt = i * 4 + (lane >> 4);
      int cg = (lane & 15) ^ (rt & 7);
      gload_lds16(kbase + (size_t)(kt * 64 + rt) * DA + cg * 8, &Ks[i * 512]);
    }
    #pragma unroll
    for (int ii = 0; ii < 2; ++ii) {            // stage Vt: 8 insts (2/wave)
      int i = w * 2 + ii;
      int rt = i * 8 + (lane >> 3);
      int cg = (lane & 7) ^ (rt & 7);
      gload_lds16(vbase + (size_t)rt * SEQ + kt * 64 + cg * 8, &Vs[i * 512]);
    }
    __syncthreads();

    // S = Qa @ Ka^T  (16q x 64k per wave)
    f32x4 sfr[4];
    #pragma unroll
    for (int nb = 0; nb < 4; ++nb) {
      f16x8 kf[4];
      int rt = nb * 16 + l16;
      #pragma unroll
      for (int ks = 0; ks < 4; ++ks)
        kf[ks] = *(const f16x8*)&Ks[rt * 128 + (((ks * 4 + g) ^ (rt & 7)) * 8)];
      f32x4 s = zero4;
      #pragma unroll
      for (int ks = 0; ks < 4; ++ks)
        s = __builtin_amdgcn_mfma_f32_16x16x32_f16(qf[ks], kf[ks], s, 0, 0, 0);
      sfr[nb] = s;
    }
    // mask (all-ones in practice; keep for correctness)
    #pragma unroll
    for (int nb = 0; nb < 4; ++nb) {
      if (mbase[kt * 64 + nb * 16 + l16] == 0) {
        #pragma unroll
        for (int r = 0; r < 4; ++r) sfr[nb][r] = -3.0e38f;
      }
    }
    // online softmax (4 q-rows per lane-group)
    #pragma unroll
    for (int r = 0; r < 4; ++r) {
      float mx = fmaxf(fmaxf(sfr[0][r], sfr[1][r]),
                       fmaxf(sfr[2][r], sfr[3][r]));
      mx = fmaxf(mx, __shfl_xor(mx, 1));
      mx = fmaxf(mx, __shfl_xor(mx, 2));
      mx = fmaxf(mx, __shfl_xor(mx, 4));
      mx = fmaxf(mx, __shfl_xor(mx, 8));
      float mnew = fmaxf(mrun[r], mx);
      float scale = exp2f((mrun[r] - mnew) * LOG2E);
      float rsum = 0.f;
      #pragma unroll
      for (int nb = 0; nb < 4; ++nb) {
        float p = exp2f((sfr[nb][r] - mnew) * LOG2E);
        sfr[nb][r] = p;
        rsum += p;
      }
      rsum += __shfl_xor(rsum, 1);
      rsum += __shfl_xor(rsum, 2);
      rsum += __shfl_xor(rsum, 4);
      rsum += __shfl_xor(rsum, 8);
      lrun[r] = lrun[r] * scale + rsum;
      mrun[r] = mnew;
      #pragma unroll
      for (int nd = 0; nd < 4; ++nd) acco[nd][r] *= scale;
    }
    // P -> wave-private LDS (swizzled), converting to f16
    #pragma unroll
    for (int r = 0; r < 4; ++r) {
      int row = g * 4 + r;
      int sw = (row & 7) << 3;
      #pragma unroll
      for (int nb = 0; nb < 4; ++nb)
        pbase[row * 64 + ((nb * 16 + l16) ^ sw)] = (_Float16)sfr[nb][r];
    }
    // O += P @ V   (reduction over 64 keys = 2 MFMA k-steps)
    #pragma unroll
    for (int ks2 = 0; ks2 < 2; ++ks2) {
      f16x8 pf = *(const f16x8*)&pbase[l16 * 64 + (((ks2 * 4 + g) ^ (l16 & 7)) * 8)];
      #pragma unroll
      for (int nd = 0; nd < 4; ++nd) {
        int row = nd * 16 + l16;
        f16x8 vf = *(const f16x8*)&Vs[row * 64 + (((ks2 * 4 + g) ^ (row & 7)) * 8)];
        acco[nd] = __builtin_amdgcn_mfma_f32_16x16x32_f16(pf, vf, acco[nd], 0, 0, 0);
      }
    }
  }

  // epilogue: AO[b,s,h*64+d] = acco / l
  #pragma unroll
  for (int r = 0; r < 4; ++r) {
    float inv = 1.0f / lrun[r];
    int sg = qt * 64 + w * 16 + g * 4 + r;
    #pragma unroll
    for (int nd = 0; nd < 4; ++nd) {
      int col = h * DH + nd * 16 + l16;
      AO[((size_t)(b * SEQ + sg)) * DM + col] = (_Float16)(acco[nd][r] * inv);
    }
  }
}

// ---------------- launch ----------------
extern "C" void kernel_launch(void* const* d_in, const int* in_sizes, int n_in,
                              void* d_out, int out_size, void* d_ws, size_t ws_size,
                              hipStream_t stream) {
  const float* x     = (const float*)d_in[0];
  const int*   mask  = (const int*)  d_in[1];
  const float* Wq    = (const float*)d_in[2];
  const float* bq    = (const float*)d_in[3];
  const float* Wk    = (const float*)d_in[4];
  const float* bk    = (const float*)d_in[5];
  const float* Wv    = (const float*)d_in[6];
  const float* bv    = (const float*)d_in[7];
  const float* Wo    = (const float*)d_in[8];
  const float* bo    = (const float*)d_in[9];
  const float* pe    = (const float*)d_in[10];
  const float* alpha = (const float*)d_in[11];
  // beta (d_in[12]) is softmax-invariant (uniform per row) -> unused

  char* ws = (char*)d_ws;
  _Float16* x16 = (_Float16*)(ws + OFF_X16);
  _Float16* wq6 = (_Float16*)(ws + OFF_WQ);
  _Float16* wk6 = (_Float16*)(ws + OFF_WK);
  _Float16* wv6 = (_Float16*)(ws + OFF_WV);
  _Float16* wo6 = (_Float16*)(ws + OFF_WO);
  _Float16* Qa  = (_Float16*)(ws + OFF_QA);
  _Float16* Ka  = (_Float16*)(ws + OFF_KA);
  _Float16* Vt  = (_Float16*)(ws + OFF_VT);
  _Float16* AO  = (_Float16*)(ws + OFF_AO);
  float* out = (float*)d_out;

  cvt_all<<<4096, 256, 0, stream>>>(x, Wq, Wk, Wv, Wo, x16);
  fill_pe<<<2048, 256, 0, stream>>>(pe, alpha, Qa, Ka);
  gemm_nt<0><<<dim3(24, 32), 256, 0, stream>>>(x16, wq6, wk6, wv6, bq, bk, bv,
                                               Qa, Ka, Vt, nullptr);
  flash_attn<<<1024, 256, 0, stream>>>(Qa, Ka, Vt, mask, AO);
  gemm_nt<1><<<dim3(8, 32), 256, 0, stream>>>(AO, wo6, nullptr, nullptr, bo,
                                              nullptr, nullptr, nullptr, nullptr,
                                              nullptr, out);
}

// Round 6
// 169.728 us; speedup vs baseline: 1.4456x; 1.3500x over previous
//
#include <hip/hip_runtime.h>

// ---------------- problem constants ----------------
#define BATCH 2
#define SEQ   2048
#define NH    16
#define DH    64
#define DA    128          // augmented head dim (content 64 + pos 64)
#define DM    1024
#define MTOT  (BATCH*SEQ)  // 4096

typedef _Float16 f16x8 __attribute__((ext_vector_type(8)));
typedef _Float16 f16x4 __attribute__((ext_vector_type(4)));
typedef float    f32x4 __attribute__((ext_vector_type(4)));

#define LOG2E 1.44269504088896340736f

// workspace offsets (bytes)
#define OFF_X16 0u
#define OFF_WQ  8388608u
#define OFF_WK  10485760u
#define OFF_WV  12582912u
#define OFF_WO  14680064u
#define OFF_QA  16777216u
#define OFF_KA  33554432u
#define OFF_VT  50331648u
#define OFF_AO  58720256u
// total 67108864 (64 MB)

__device__ __forceinline__ void gload_lds16(const _Float16* g, _Float16* l) {
  __builtin_amdgcn_global_load_lds(
      (const __attribute__((address_space(1))) unsigned int*)g,
      (__attribute__((address_space(3))) unsigned int*)l, 16, 0, 0);
}

__device__ __forceinline__ float fexp2(float x) {
  float r;
  asm("v_exp_f32 %0, %1" : "=v"(r) : "v"(x));
  return r;
}

// ---------------- fp32 -> fp16 conversion (x + 4 weights) ----------------
__global__ __launch_bounds__(256) void cvt_all(
    const float* __restrict__ x,  const float* __restrict__ wq,
    const float* __restrict__ wk, const float* __restrict__ wv,
    const float* __restrict__ wo, _Float16* __restrict__ dst)
{
  int i = blockIdx.x * 256 + threadIdx.x;   // each thread: 8 floats
  const float* src;
  if (i < 524288) {
    src = x + (size_t)i * 8;
  } else {
    int j = i - 524288;
    int wi = j >> 17;                        // 131072 threads per weight
    const float* w = (wi == 0) ? wq : ((wi == 1) ? wk : ((wi == 2) ? wv : wo));
    src = w + (size_t)(j & 131071) * 8;
  }
  float4 a = ((const float4*)src)[0];
  float4 c = ((const float4*)src)[1];
  f16x8 hv;
  hv[0]=(_Float16)a.x; hv[1]=(_Float16)a.y; hv[2]=(_Float16)a.z; hv[3]=(_Float16)a.w;
  hv[4]=(_Float16)c.x; hv[5]=(_Float16)c.y; hv[6]=(_Float16)c.z; hv[7]=(_Float16)c.w;
  *(f16x8*)(dst + (size_t)i * 8) = hv;
}

// ---------------- fill positional halves of Qa/Ka (8-wide vectorized) -------
// Qa[b,h,s,64+d] = alpha[h]*LOG2E*pe[s,d] ; Ka[b,h,s,64+d] = pe[s,d]
// (LOG2E folded into Q so flash softmax can use exp2 directly)
__global__ __launch_bounds__(256) void fill_pe(
    const float* __restrict__ pe, const float* __restrict__ alpha,
    _Float16* __restrict__ Qa, _Float16* __restrict__ Ka)
{
  int idx = blockIdx.x * 256 + threadIdx.x;   // B*H*S*8 = 2^19 threads
  int c8 = idx & 7;
  int s  = (idx >> 3) & 2047;
  int h  = (idx >> 14) & 15;
  int b  = idx >> 18;
  const float4* p4 = (const float4*)(pe + s * 64 + c8 * 8);
  float4 a = p4[0], c = p4[1];
  float al = alpha[h] * LOG2E;
  f16x8 hk, hq;
  hk[0]=(_Float16)a.x; hk[1]=(_Float16)a.y; hk[2]=(_Float16)a.z; hk[3]=(_Float16)a.w;
  hk[4]=(_Float16)c.x; hk[5]=(_Float16)c.y; hk[6]=(_Float16)c.z; hk[7]=(_Float16)c.w;
  hq[0]=(_Float16)(al*a.x); hq[1]=(_Float16)(al*a.y); hq[2]=(_Float16)(al*a.z); hq[3]=(_Float16)(al*a.w);
  hq[4]=(_Float16)(al*c.x); hq[5]=(_Float16)(al*c.y); hq[6]=(_Float16)(al*c.z); hq[7]=(_Float16)(al*c.w);
  size_t o = ((size_t)((b * NH + h) * SEQ + s)) * DA + 64 + c8 * 8;
  *(f16x8*)&Qa[o] = hq;
  *(f16x8*)&Ka[o] = hk;
}

// ---------------- NT GEMM: C(M x N) = A(M x K) * W(N x K)^T ----------------
template<int MODE>
__global__ __launch_bounds__(256) void gemm_nt(
    const _Float16* __restrict__ A,
    const _Float16* __restrict__ W0, const _Float16* __restrict__ W1,
    const _Float16* __restrict__ W2,
    const float* __restrict__ b0, const float* __restrict__ b1,
    const float* __restrict__ b2,
    _Float16* __restrict__ Qa, _Float16* __restrict__ Ka,
    _Float16* __restrict__ Vt, float* __restrict__ Out)
{
  __shared__ _Float16 As[128 * 64];
  __shared__ _Float16 Bs[128 * 64];
  const int tid = threadIdx.x;
  const int w = tid >> 6, lane = tid & 63;
  const int g = lane >> 4, l16 = lane & 15;
  const int wm = w >> 1, wn = w & 1;

  int nb_all = blockIdx.x;
  int mblk = blockIdx.y;
  const _Float16* Bp; const float* biasp;
  int which = 0, nblk = nb_all;
  if (MODE == 0) {
    which = nb_all >> 3; nblk = nb_all & 7;
    Bp = (which == 0) ? W0 : ((which == 1) ? W1 : W2);
    biasp = (which == 0) ? b0 : ((which == 1) ? b1 : b2);
  } else {
    Bp = W0; biasp = b0;
  }

  f32x4 zero4 = {0.f, 0.f, 0.f, 0.f};
  f32x4 acc[4][4];
  #pragma unroll
  for (int mb = 0; mb < 4; ++mb)
    #pragma unroll
    for (int nb = 0; nb < 4; ++nb) acc[mb][nb] = zero4;

  const _Float16* Abase = A  + (size_t)mblk * 128 * DM;
  const _Float16* Bbase = Bp + (size_t)nblk * 128 * DM;

  for (int kt = 0; kt < DM / 64; ++kt) {
    __syncthreads();
    #pragma unroll
    for (int ii = 0; ii < 4; ++ii) {
      int i = w * 4 + ii;
      int rt = i * 8 + (lane >> 3);
      int cg = (lane & 7) ^ (rt & 7);
      gload_lds16(Abase + (size_t)rt * DM + kt * 64 + cg * 8, &As[i * 512]);
    }
    #pragma unroll
    for (int ii = 0; ii < 4; ++ii) {
      int i = w * 4 + ii;
      int rt = i * 8 + (lane >> 3);
      int cg = (lane & 7) ^ (rt & 7);
      gload_lds16(Bbase + (size_t)rt * DM + kt * 64 + cg * 8, &Bs[i * 512]);
    }
    __syncthreads();
    #pragma unroll
    for (int ks = 0; ks < 2; ++ks) {
      f16x8 av[4], bv[4];
      #pragma unroll
      for (int mb = 0; mb < 4; ++mb) {
        int rt = wm * 64 + mb * 16 + l16;
        av[mb] = *(const f16x8*)&As[rt * 64 + (((ks * 4 + g) ^ (rt & 7)) * 8)];
      }
      #pragma unroll
      for (int nb = 0; nb < 4; ++nb) {
        int rt = wn * 64 + nb * 16 + l16;
        bv[nb] = *(const f16x8*)&Bs[rt * 64 + (((ks * 4 + g) ^ (rt & 7)) * 8)];
      }
      #pragma unroll
      for (int mb = 0; mb < 4; ++mb)
        #pragma unroll
        for (int nb = 0; nb < 4; ++nb)
          acc[mb][nb] = __builtin_amdgcn_mfma_f32_16x16x32_f16(
              av[mb], bv[nb], acc[mb][nb], 0, 0, 0);
    }
  }

  // epilogue
  #pragma unroll
  for (int nb = 0; nb < 4; ++nb) {
    int n = nblk * 128 + wn * 64 + nb * 16 + l16;
    float bias = biasp[n];
    #pragma unroll
    for (int mb = 0; mb < 4; ++mb) {
      int m0 = mblk * 128 + wm * 64 + mb * 16 + g * 4;
      if (MODE == 0) {
        int hh = n >> 6, dd = n & 63;
        if (which == 2) {                    // V: write transposed Vt[bh,d,s]
          int bb = m0 >> 11, ss = m0 & 2047;
          f16x4 hv;
          #pragma unroll
          for (int r = 0; r < 4; ++r) hv[r] = (_Float16)(acc[mb][nb][r] + bias);
          *(f16x4*)&Vt[((size_t)((bb * NH + hh) * DH + dd)) * SEQ + ss] = hv;
        } else {
          #pragma unroll
          for (int r = 0; r < 4; ++r) {
            int m = m0 + r; int bb = m >> 11, ss = m & 2047;
            size_t o = ((size_t)((bb * NH + hh) * SEQ + ss)) * DA + dd;
            // Q gets 1/sqrt(64) * LOG2E folded in (softmax uses exp2)
            if (which == 0) Qa[o] = (_Float16)((acc[mb][nb][r] + bias) * (0.125f * LOG2E));
            else            Ka[o] = (_Float16)(acc[mb][nb][r] + bias);
          }
        }
      } else {
        #pragma unroll
        for (int r = 0; r < 4; ++r)
          Out[(size_t)(m0 + r) * DM + n] = acc[mb][nb][r] + bias;
      }
    }
  }
}

// ---------------- flash attention (swapped QK^T, dbuf K/V) ----------------
// grid: 512 blocks (XCD-pinned); 8 waves x 16 q-rows = 128 q-rows per block.
// Swapped MFMA: lane holds S[16 keys][q=l16] -> per-lane row softmax.
// K/V double-buffered, raw barriers + counted vmcnt(6) keep prefetch in flight.
__global__ __launch_bounds__(512, 4) void flash_attn(
    const _Float16* __restrict__ Qa, const _Float16* __restrict__ Ka,
    const _Float16* __restrict__ Vt, const int* __restrict__ mask,
    _Float16* __restrict__ AO)
{
  __shared__ _Float16 Ks[2][64 * 128];  // 2 x 16KB
  __shared__ _Float16 Vs[2][64 * 64];   // 2 x 8KB
  __shared__ _Float16 Ps[8][1024];      // 8 x 2KB (wave-private P)
  const int tid = threadIdx.x;
  const int w = tid >> 6, lane = tid & 63;
  const int g = lane >> 4, l16 = lane & 15;

  int bid = blockIdx.x;                  // 512 blocks: bid&7 -> XCD
  int work = (bid & 7) * 64 + (bid >> 3);
  const int qt = work & 15;              // 16 q-tiles of 128
  const int bh = work >> 4;              // 4 bh per XCD -> K/V L2-resident
  const int h = bh & 15, b = bh >> 4;

  // Q fragment (16 q-rows per wave; content pre-scaled by 0.125*LOG2E,
  // pos half by alpha*LOG2E upstream)
  const _Float16* qbase = Qa + ((size_t)(bh * SEQ) + qt * 128 + w * 16) * DA;
  f16x8 qf[4];
  #pragma unroll
  for (int ks = 0; ks < 4; ++ks)
    qf[ks] = *(const f16x8*)&qbase[l16 * DA + ks * 32 + g * 8];

  f32x4 zero4 = {0.f, 0.f, 0.f, 0.f};
  f32x4 acco[4];
  #pragma unroll
  for (int nd = 0; nd < 4; ++nd) acco[nd] = zero4;
  float mrun = -3.0e38f, lrun = 0.f;

  const _Float16* kbase = Ka + (size_t)bh * SEQ * DA;
  const _Float16* vbase = Vt + (size_t)bh * DH * SEQ;
  const int* mbase = mask + b * SEQ;
  char* pby = (char*)&Ps[w][0] + l16 * 128;
  const int sw = (l16 & 14) << 3;       // P byte-swizzle (16B granular)
  int bidx[4];
  #pragma unroll
  for (int r = 0; r < 4; ++r) bidx[r] = ((lane & 48) | (g * 4 + r)) << 2;

  auto STAGE = [&](int buf, int kt) {
    #pragma unroll
    for (int ii = 0; ii < 2; ++ii) {          // K: 1024 16B-chunks / 512 thr
      int i = ii * 512 + tid;
      int rt = i >> 4, c = i & 15;
      int cg = c ^ (rt & 7);
      gload_lds16(kbase + (size_t)(kt * 64 + rt) * DA + cg * 8, &Ks[buf][i * 8]);
    }
    {                                         // V: 512 chunks / 512 thr
      int i = tid;
      int rt = i >> 3, c = i & 7;
      int cg = c ^ (rt & 7);
      gload_lds16(vbase + (size_t)rt * SEQ + kt * 64 + cg * 8, &Vs[buf][i * 8]);
    }
  };

  STAGE(0, 0);
  int cur = 0;
  for (int kt = 0; kt < SEQ / 64; ++kt) {
    // (a) all waves done reading the buffer we are about to overwrite
    asm volatile("s_waitcnt lgkmcnt(0)" ::: "memory");
    __builtin_amdgcn_s_barrier();
    asm volatile("" ::: "memory");
    if (kt + 1 < SEQ / 64) {
      STAGE(cur ^ 1, kt + 1);                 // prefetch next tile
      asm volatile("s_waitcnt vmcnt(6)" ::: "memory");  // tile kt landed
    } else {
      asm volatile("s_waitcnt vmcnt(0)" ::: "memory");
    }
    __builtin_amdgcn_s_barrier();             // (b) tile kt visible to all
    asm volatile("" ::: "memory");

    // swapped QK^T: S^T[key][q]; lane holds S[keys nb*16+g*4+r][q=l16]
    f32x4 sfr[4];
    #pragma unroll
    for (int nb = 0; nb < 4; ++nb) {
      f16x8 kf[4];
      int rt = nb * 16 + l16;
      #pragma unroll
      for (int ks = 0; ks < 4; ++ks)
        kf[ks] = *(const f16x8*)&Ks[cur][rt * 128 + (((ks * 4 + g) ^ (rt & 7)) * 8)];
      f32x4 s = zero4;
      #pragma unroll
      for (int ks = 0; ks < 4; ++ks)
        s = __builtin_amdgcn_mfma_f32_16x16x32_f16(kf[ks], qf[ks], s, 0, 0, 0);
      sfr[nb] = s;
    }

    // per-lane online softmax for q = l16 (scores already in log2 units)
    float mx = sfr[0][0];
    #pragma unroll
    for (int nb = 0; nb < 4; ++nb)
      #pragma unroll
      for (int r = 0; r < 4; ++r) mx = fmaxf(mx, sfr[nb][r]);
    mx = fmaxf(mx, __shfl_xor(mx, 16));
    mx = fmaxf(mx, __shfl_xor(mx, 32));
    float mnew = fmaxf(mrun, mx);
    float scale = fexp2(mrun - mnew);
    float rsum = 0.f;
    #pragma unroll
    for (int nb = 0; nb < 4; ++nb) {
      const int4 mv = *(const int4*)&mbase[kt * 64 + nb * 16 + g * 4];
      float pv[4];
      #pragma unroll
      for (int r = 0; r < 4; ++r) {
        int mr = (r == 0) ? mv.x : (r == 1) ? mv.y : (r == 2) ? mv.z : mv.w;
        float p = fexp2(sfr[nb][r] - mnew);
        p = (mr != 0) ? p : 0.f;               // mask post-exp (softmax-equiv)
        pv[r] = p; rsum += p;
      }
      f16x4 w4;
      w4[0]=(_Float16)pv[0]; w4[1]=(_Float16)pv[1];
      w4[2]=(_Float16)pv[2]; w4[3]=(_Float16)pv[3];
      *(f16x4*)(pby + (((nb * 32 + g * 8)) ^ sw)) = w4;   // packed b64, swizzled
    }
    rsum += __shfl_xor(rsum, 16);
    rsum += __shfl_xor(rsum, 32);
    lrun = lrun * scale + rsum;
    mrun = mnew;
    // broadcast scale (per q=l16) to acco rows q=4g+r
    float sc[4];
    #pragma unroll
    for (int r = 0; r < 4; ++r)
      sc[r] = __int_as_float(__builtin_amdgcn_ds_bpermute(bidx[r], __float_as_int(scale)));
    #pragma unroll
    for (int nd = 0; nd < 4; ++nd)
      #pragma unroll
      for (int r = 0; r < 4; ++r) acco[nd][r] *= sc[r];

    // O += P @ V (2 k-steps)
    #pragma unroll
    for (int ks2 = 0; ks2 < 2; ++ks2) {
      f16x8 pf = *(const f16x8*)(pby + ((ks2 * 64 + g * 16) ^ sw));
      #pragma unroll
      for (int nd = 0; nd < 4; ++nd) {
        int row = nd * 16 + l16;
        f16x8 vf = *(const f16x8*)&Vs[cur][row * 64 + (((ks2 * 4 + g) ^ (row & 7)) * 8)];
        acco[nd] = __builtin_amdgcn_mfma_f32_16x16x32_f16(pf, vf, acco[nd], 0, 0, 0);
      }
    }
    cur ^= 1;
  }

  // epilogue: AO[b,s,h*64+d] = acco / l   (broadcast 1/l to rows 4g+r)
  float inv = 1.0f / lrun;
  float iv[4];
  #pragma unroll
  for (int r = 0; r < 4; ++r)
    iv[r] = __int_as_float(__builtin_amdgcn_ds_bpermute(bidx[r], __float_as_int(inv)));
  #pragma unroll
  for (int r = 0; r < 4; ++r) {
    int sg = qt * 128 + w * 16 + g * 4 + r;
    #pragma unroll
    for (int nd = 0; nd < 4; ++nd) {
      int col = h * DH + nd * 16 + l16;
      AO[((size_t)(b * SEQ + sg)) * DM + col] = (_Float16)(acco[nd][r] * iv[r]);
    }
  }
}

// ---------------- launch ----------------
extern "C" void kernel_launch(void* const* d_in, const int* in_sizes, int n_in,
                              void* d_out, int out_size, void* d_ws, size_t ws_size,
                              hipStream_t stream) {
  const float* x     = (const float*)d_in[0];
  const int*   mask  = (const int*)  d_in[1];
  const float* Wq    = (const float*)d_in[2];
  const float* bq    = (const float*)d_in[3];
  const float* Wk    = (const float*)d_in[4];
  const float* bk    = (const float*)d_in[5];
  const float* Wv    = (const float*)d_in[6];
  const float* bv    = (const float*)d_in[7];
  const float* Wo    = (const float*)d_in[8];
  const float* bo    = (const float*)d_in[9];
  const float* pe    = (const float*)d_in[10];
  const float* alpha = (const float*)d_in[11];
  // beta (d_in[12]) is softmax-invariant (uniform per row) -> unused

  char* ws = (char*)d_ws;
  _Float16* x16 = (_Float16*)(ws + OFF_X16);
  _Float16* wq6 = (_Float16*)(ws + OFF_WQ);
  _Float16* wk6 = (_Float16*)(ws + OFF_WK);
  _Float16* wv6 = (_Float16*)(ws + OFF_WV);
  _Float16* wo6 = (_Float16*)(ws + OFF_WO);
  _Float16* Qa  = (_Float16*)(ws + OFF_QA);
  _Float16* Ka  = (_Float16*)(ws + OFF_KA);
  _Float16* Vt  = (_Float16*)(ws + OFF_VT);
  _Float16* AO  = (_Float16*)(ws + OFF_AO);
  float* out = (float*)d_out;

  cvt_all<<<4096, 256, 0, stream>>>(x, Wq, Wk, Wv, Wo, x16);
  fill_pe<<<2048, 256, 0, stream>>>(pe, alpha, Qa, Ka);
  gemm_nt<0><<<dim3(24, 32), 256, 0, stream>>>(x16, wq6, wk6, wv6, bq, bk, bv,
                                               Qa, Ka, Vt, nullptr);
  flash_attn<<<512, 512, 0, stream>>>(Qa, Ka, Vt, mask, AO);
  gemm_nt<1><<<dim3(8, 32), 256, 0, stream>>>(AO, wo6, nullptr, nullptr, bo,
                                              nullptr, nullptr, nullptr, nullptr,
                                              nullptr, out);
}

// Round 7
// 161.374 us; speedup vs baseline: 1.5204x; 1.0518x over previous
//
#include <hip/hip_runtime.h>

// ---------------- problem constants ----------------
#define BATCH 2
#define SEQ   2048
#define NH    16
#define DH    64
#define DA    128          // augmented head dim (content 64 + pos 64)
#define DM    1024
#define MTOT  (BATCH*SEQ)  // 4096

typedef _Float16 f16x8 __attribute__((ext_vector_type(8)));
typedef _Float16 f16x4 __attribute__((ext_vector_type(4)));
typedef float    f32x4 __attribute__((ext_vector_type(4)));

#define LOG2E 1.44269504088896340736f

// workspace offsets (bytes)
#define OFF_X16 0u
#define OFF_WQ  8388608u
#define OFF_WK  10485760u
#define OFF_WV  12582912u
#define OFF_WO  14680064u
#define OFF_QA  16777216u
#define OFF_KA  33554432u
#define OFF_VT  50331648u
#define OFF_AO  58720256u
// total 67108864 (64 MB)

__device__ __forceinline__ void gload_lds16(const _Float16* g, _Float16* l) {
  __builtin_amdgcn_global_load_lds(
      (const __attribute__((address_space(1))) unsigned int*)g,
      (__attribute__((address_space(3))) unsigned int*)l, 16, 0, 0);
}

__device__ __forceinline__ float fexp2(float x) {
  float r;
  asm("v_exp_f32 %0, %1" : "=v"(r) : "v"(x));
  return r;
}

// ---------------- fp32 -> fp16 conversion (x + 4 weights) ----------------
__global__ __launch_bounds__(256) void cvt_all(
    const float* __restrict__ x,  const float* __restrict__ wq,
    const float* __restrict__ wk, const float* __restrict__ wv,
    const float* __restrict__ wo, _Float16* __restrict__ dst)
{
  int i = blockIdx.x * 256 + threadIdx.x;   // each thread: 8 floats
  const float* src;
  if (i < 524288) {
    src = x + (size_t)i * 8;
  } else {
    int j = i - 524288;
    int wi = j >> 17;                        // 131072 threads per weight
    const float* w = (wi == 0) ? wq : ((wi == 1) ? wk : ((wi == 2) ? wv : wo));
    src = w + (size_t)(j & 131071) * 8;
  }
  float4 a = ((const float4*)src)[0];
  float4 c = ((const float4*)src)[1];
  f16x8 hv;
  hv[0]=(_Float16)a.x; hv[1]=(_Float16)a.y; hv[2]=(_Float16)a.z; hv[3]=(_Float16)a.w;
  hv[4]=(_Float16)c.x; hv[5]=(_Float16)c.y; hv[6]=(_Float16)c.z; hv[7]=(_Float16)c.w;
  *(f16x8*)(dst + (size_t)i * 8) = hv;
}

// ---------------- fill positional halves of Qa/Ka (8-wide vectorized) -------
// Qa[b,h,s,64+d] = alpha[h]*LOG2E*pe[s,d] ; Ka[b,h,s,64+d] = pe[s,d]
__global__ __launch_bounds__(256) void fill_pe(
    const float* __restrict__ pe, const float* __restrict__ alpha,
    _Float16* __restrict__ Qa, _Float16* __restrict__ Ka)
{
  int idx = blockIdx.x * 256 + threadIdx.x;   // B*H*S*8 = 2^19 threads
  int c8 = idx & 7;
  int s  = (idx >> 3) & 2047;
  int h  = (idx >> 14) & 15;
  int b  = idx >> 18;
  const float4* p4 = (const float4*)(pe + s * 64 + c8 * 8);
  float4 a = p4[0], c = p4[1];
  float al = alpha[h] * LOG2E;
  f16x8 hk, hq;
  hk[0]=(_Float16)a.x; hk[1]=(_Float16)a.y; hk[2]=(_Float16)a.z; hk[3]=(_Float16)a.w;
  hk[4]=(_Float16)c.x; hk[5]=(_Float16)c.y; hk[6]=(_Float16)c.z; hk[7]=(_Float16)c.w;
  hq[0]=(_Float16)(al*a.x); hq[1]=(_Float16)(al*a.y); hq[2]=(_Float16)(al*a.z); hq[3]=(_Float16)(al*a.w);
  hq[4]=(_Float16)(al*c.x); hq[5]=(_Float16)(al*c.y); hq[6]=(_Float16)(al*c.z); hq[7]=(_Float16)(al*c.w);
  size_t o = ((size_t)((b * NH + h) * SEQ + s)) * DA + 64 + c8 * 8;
  *(f16x8*)&Qa[o] = hq;
  *(f16x8*)&Ka[o] = hk;
}

// ---------------- NT GEMM: C(M x N) = A(M x K) * W(N x K)^T ----------------
template<int MODE>
__global__ __launch_bounds__(256) void gemm_nt(
    const _Float16* __restrict__ A,
    const _Float16* __restrict__ W0, const _Float16* __restrict__ W1,
    const _Float16* __restrict__ W2,
    const float* __restrict__ b0, const float* __restrict__ b1,
    const float* __restrict__ b2,
    _Float16* __restrict__ Qa, _Float16* __restrict__ Ka,
    _Float16* __restrict__ Vt, float* __restrict__ Out)
{
  __shared__ _Float16 As[128 * 64];
  __shared__ _Float16 Bs[128 * 64];
  const int tid = threadIdx.x;
  const int w = tid >> 6, lane = tid & 63;
  const int g = lane >> 4, l16 = lane & 15;
  const int wm = w >> 1, wn = w & 1;

  int nb_all = blockIdx.x;
  int mblk = blockIdx.y;
  const _Float16* Bp; const float* biasp;
  int which = 0, nblk = nb_all;
  if (MODE == 0) {
    which = nb_all >> 3; nblk = nb_all & 7;
    Bp = (which == 0) ? W0 : ((which == 1) ? W1 : W2);
    biasp = (which == 0) ? b0 : ((which == 1) ? b1 : b2);
  } else {
    Bp = W0; biasp = b0;
  }

  f32x4 zero4 = {0.f, 0.f, 0.f, 0.f};
  f32x4 acc[4][4];
  #pragma unroll
  for (int mb = 0; mb < 4; ++mb)
    #pragma unroll
    for (int nb = 0; nb < 4; ++nb) acc[mb][nb] = zero4;

  const _Float16* Abase = A  + (size_t)mblk * 128 * DM;
  const _Float16* Bbase = Bp + (size_t)nblk * 128 * DM;

  for (int kt = 0; kt < DM / 64; ++kt) {
    __syncthreads();
    #pragma unroll
    for (int ii = 0; ii < 4; ++ii) {
      int i = w * 4 + ii;
      int rt = i * 8 + (lane >> 3);
      int cg = (lane & 7) ^ (rt & 7);
      gload_lds16(Abase + (size_t)rt * DM + kt * 64 + cg * 8, &As[i * 512]);
    }
    #pragma unroll
    for (int ii = 0; ii < 4; ++ii) {
      int i = w * 4 + ii;
      int rt = i * 8 + (lane >> 3);
      int cg = (lane & 7) ^ (rt & 7);
      gload_lds16(Bbase + (size_t)rt * DM + kt * 64 + cg * 8, &Bs[i * 512]);
    }
    __syncthreads();
    #pragma unroll
    for (int ks = 0; ks < 2; ++ks) {
      f16x8 av[4], bv[4];
      #pragma unroll
      for (int mb = 0; mb < 4; ++mb) {
        int rt = wm * 64 + mb * 16 + l16;
        av[mb] = *(const f16x8*)&As[rt * 64 + (((ks * 4 + g) ^ (rt & 7)) * 8)];
      }
      #pragma unroll
      for (int nb = 0; nb < 4; ++nb) {
        int rt = wn * 64 + nb * 16 + l16;
        bv[nb] = *(const f16x8*)&Bs[rt * 64 + (((ks * 4 + g) ^ (rt & 7)) * 8)];
      }
      #pragma unroll
      for (int mb = 0; mb < 4; ++mb)
        #pragma unroll
        for (int nb = 0; nb < 4; ++nb)
          acc[mb][nb] = __builtin_amdgcn_mfma_f32_16x16x32_f16(
              av[mb], bv[nb], acc[mb][nb], 0, 0, 0);
    }
  }

  // epilogue
  #pragma unroll
  for (int nb = 0; nb < 4; ++nb) {
    int n = nblk * 128 + wn * 64 + nb * 16 + l16;
    float bias = biasp[n];
    #pragma unroll
    for (int mb = 0; mb < 4; ++mb) {
      int m0 = mblk * 128 + wm * 64 + mb * 16 + g * 4;
      if (MODE == 0) {
        int hh = n >> 6, dd = n & 63;
        if (which == 2) {                    // V: write transposed Vt[bh,d,s]
          int bb = m0 >> 11, ss = m0 & 2047;
          f16x4 hv;
          #pragma unroll
          for (int r = 0; r < 4; ++r) hv[r] = (_Float16)(acc[mb][nb][r] + bias);
          *(f16x4*)&Vt[((size_t)((bb * NH + hh) * DH + dd)) * SEQ + ss] = hv;
        } else {
          #pragma unroll
          for (int r = 0; r < 4; ++r) {
            int m = m0 + r; int bb = m >> 11, ss = m & 2047;
            size_t o = ((size_t)((bb * NH + hh) * SEQ + ss)) * DA + dd;
            if (which == 0) Qa[o] = (_Float16)((acc[mb][nb][r] + bias) * (0.125f * LOG2E));
            else            Ka[o] = (_Float16)(acc[mb][nb][r] + bias);
          }
        }
      } else {
        #pragma unroll
        for (int r = 0; r < 4; ++r)
          Out[(size_t)(m0 + r) * DM + n] = acc[mb][nb][r] + bias;
      }
    }
  }
}

// ---------------- flash attention (swapped QK^T, dbuf K/V) ----------------
// 512 blocks (XCD-pinned); 8 waves x 16 q-rows. Swapped MFMA -> per-lane
// row softmax; mask hoisted to wave-uniform precheck; defer-max (THR=8);
// setprio around MFMA clusters; counted vmcnt(6) keeps prefetch in flight.
__global__ __launch_bounds__(512, 4) void flash_attn(
    const _Float16* __restrict__ Qa, const _Float16* __restrict__ Ka,
    const _Float16* __restrict__ Vt, const int* __restrict__ mask,
    _Float16* __restrict__ AO)
{
  __shared__ _Float16 Ks[2][64 * 128];  // 2 x 16KB
  __shared__ _Float16 Vs[2][64 * 64];   // 2 x 8KB
  __shared__ _Float16 Ps[8][1024];      // 8 x 2KB (wave-private P)
  const int tid = threadIdx.x;
  const int w = tid >> 6, lane = tid & 63;
  const int g = lane >> 4, l16 = lane & 15;

  int bid = blockIdx.x;                  // 512 blocks: bid&7 -> XCD
  int work = (bid & 7) * 64 + (bid >> 3);
  const int qt = work & 15;              // 16 q-tiles of 128
  const int bh = work >> 4;              // 4 bh per XCD -> K/V L2-resident
  const int h = bh & 15, b = bh >> 4;

  const _Float16* qbase = Qa + ((size_t)(bh * SEQ) + qt * 128 + w * 16) * DA;
  f16x8 qf[4];
  #pragma unroll
  for (int ks = 0; ks < 4; ++ks)
    qf[ks] = *(const f16x8*)&qbase[l16 * DA + ks * 32 + g * 8];

  f32x4 zero4 = {0.f, 0.f, 0.f, 0.f};
  f32x4 acco[4];
  #pragma unroll
  for (int nd = 0; nd < 4; ++nd) acco[nd] = zero4;
  float mrun = -3.0e38f, lrun = 0.f;

  const _Float16* kbase = Ka + (size_t)bh * SEQ * DA;
  const _Float16* vbase = Vt + (size_t)bh * DH * SEQ;
  const int* mbase = mask + b * SEQ;
  char* pby = (char*)&Ps[w][0] + l16 * 128;
  const int sw = (l16 & 14) << 3;       // P byte-swizzle (16B granular)
  int bidx[4];
  #pragma unroll
  for (int r = 0; r < 4; ++r) bidx[r] = ((lane & 48) | (g * 4 + r)) << 2;

  // wave-uniform mask precheck over the whole sequence (all-ones in practice)
  int allm = 1;
  #pragma unroll 8
  for (int t = 0; t < SEQ / 64; ++t) allm &= (mbase[t * 64 + lane] != 0);
  const bool maskclean = __all(allm);

  auto STAGE = [&](int buf, int kt) {
    #pragma unroll
    for (int ii = 0; ii < 2; ++ii) {          // K: 1024 16B-chunks / 512 thr
      int i = ii * 512 + tid;
      int rt = i >> 4, c = i & 15;
      int cg = c ^ (rt & 7);
      gload_lds16(kbase + (size_t)(kt * 64 + rt) * DA + cg * 8, &Ks[buf][i * 8]);
    }
    {                                         // V: 512 chunks / 512 thr
      int i = tid;
      int rt = i >> 3, c = i & 7;
      int cg = c ^ (rt & 7);
      gload_lds16(vbase + (size_t)rt * SEQ + kt * 64 + cg * 8, &Vs[buf][i * 8]);
    }
  };

  STAGE(0, 0);
  int cur = 0;
  for (int kt = 0; kt < SEQ / 64; ++kt) {
    // (a) all waves done reading the buffer we are about to overwrite
    asm volatile("s_waitcnt lgkmcnt(0)" ::: "memory");
    __builtin_amdgcn_s_barrier();
    asm volatile("" ::: "memory");
    if (kt + 1 < SEQ / 64) {
      STAGE(cur ^ 1, kt + 1);                 // prefetch next tile
      asm volatile("s_waitcnt vmcnt(6)" ::: "memory");  // tile kt landed
    } else {
      asm volatile("s_waitcnt vmcnt(0)" ::: "memory");
    }
    __builtin_amdgcn_s_barrier();             // (b) tile kt visible to all
    asm volatile("" ::: "memory");

    // swapped QK^T: S^T[key][q]; lane holds S[keys nb*16+g*4+r][q=l16]
    f32x4 sfr[4];
    __builtin_amdgcn_s_setprio(1);
    #pragma unroll
    for (int nb = 0; nb < 4; ++nb) {
      f16x8 kf[4];
      int rt = nb * 16 + l16;
      #pragma unroll
      for (int ks = 0; ks < 4; ++ks)
        kf[ks] = *(const f16x8*)&Ks[cur][rt * 128 + (((ks * 4 + g) ^ (rt & 7)) * 8)];
      f32x4 s = zero4;
      #pragma unroll
      for (int ks = 0; ks < 4; ++ks)
        s = __builtin_amdgcn_mfma_f32_16x16x32_f16(kf[ks], qf[ks], s, 0, 0, 0);
      sfr[nb] = s;
    }
    __builtin_amdgcn_s_setprio(0);

    // rare slow path: apply mask pre-max (never taken for all-ones mask)
    if (!maskclean) {
      #pragma unroll
      for (int nb = 0; nb < 4; ++nb) {
        const int4 mv = *(const int4*)&mbase[kt * 64 + nb * 16 + g * 4];
        #pragma unroll
        for (int r = 0; r < 4; ++r) {
          int mr = (r == 0) ? mv.x : (r == 1) ? mv.y : (r == 2) ? mv.z : mv.w;
          if (mr == 0) sfr[nb][r] = -3.0e38f;
        }
      }
    }

    // per-lane online softmax for q = l16 (scores already in log2 units)
    float mx = sfr[0][0];
    #pragma unroll
    for (int nb = 0; nb < 4; ++nb)
      #pragma unroll
      for (int r = 0; r < 4; ++r) mx = fmaxf(mx, sfr[nb][r]);
    mx = fmaxf(mx, __shfl_xor(mx, 16));
    mx = fmaxf(mx, __shfl_xor(mx, 32));

    // defer-max (T13): only rescale when max grew beyond THR=8 (log2 units)
    const bool rescale = !__all(mx <= mrun + 8.0f);
    float mnew = mrun, scale = 1.0f;
    if (rescale) {
      mnew = fmaxf(mrun, mx);
      scale = fexp2(mrun - mnew);
    }
    float rsum = 0.f;
    #pragma unroll
    for (int nb = 0; nb < 4; ++nb) {
      float pv[4];
      #pragma unroll
      for (int r = 0; r < 4; ++r) {
        float p = fexp2(sfr[nb][r] - mnew);
        pv[r] = p; rsum += p;
      }
      f16x4 w4;
      w4[0]=(_Float16)pv[0]; w4[1]=(_Float16)pv[1];
      w4[2]=(_Float16)pv[2]; w4[3]=(_Float16)pv[3];
      *(f16x4*)(pby + (((nb * 32 + g * 8)) ^ sw)) = w4;   // packed b64, swizzled
    }
    rsum += __shfl_xor(rsum, 16);
    rsum += __shfl_xor(rsum, 32);
    if (rescale) {
      lrun = lrun * scale + rsum;
      mrun = mnew;
      float sc[4];
      #pragma unroll
      for (int r = 0; r < 4; ++r)
        sc[r] = __int_as_float(__builtin_amdgcn_ds_bpermute(bidx[r], __float_as_int(scale)));
      #pragma unroll
      for (int nd = 0; nd < 4; ++nd)
        #pragma unroll
        for (int r = 0; r < 4; ++r) acco[nd][r] *= sc[r];
    } else {
      lrun += rsum;
    }

    // O += P @ V (2 k-steps)
    __builtin_amdgcn_s_setprio(1);
    #pragma unroll
    for (int ks2 = 0; ks2 < 2; ++ks2) {
      f16x8 pf = *(const f16x8*)(pby + ((ks2 * 64 + g * 16) ^ sw));
      #pragma unroll
      for (int nd = 0; nd < 4; ++nd) {
        int row = nd * 16 + l16;
        f16x8 vf = *(const f16x8*)&Vs[cur][row * 64 + (((ks2 * 4 + g) ^ (row & 7)) * 8)];
        acco[nd] = __builtin_amdgcn_mfma_f32_16x16x32_f16(pf, vf, acco[nd], 0, 0, 0);
      }
    }
    __builtin_amdgcn_s_setprio(0);
    cur ^= 1;
  }

  // epilogue: AO[b,s,h*64+d] = acco / l   (broadcast 1/l to rows 4g+r)
  float inv = 1.0f / lrun;
  float iv[4];
  #pragma unroll
  for (int r = 0; r < 4; ++r)
    iv[r] = __int_as_float(__builtin_amdgcn_ds_bpermute(bidx[r], __float_as_int(inv)));
  #pragma unroll
  for (int r = 0; r < 4; ++r) {
    int sg = qt * 128 + w * 16 + g * 4 + r;
    #pragma unroll
    for (int nd = 0; nd < 4; ++nd) {
      int col = h * DH + nd * 16 + l16;
      AO[((size_t)(b * SEQ + sg)) * DM + col] = (_Float16)(acco[nd][r] * iv[r]);
    }
  }
}

// ---------------- launch ----------------
extern "C" void kernel_launch(void* const* d_in, const int* in_sizes, int n_in,
                              void* d_out, int out_size, void* d_ws, size_t ws_size,
                              hipStream_t stream) {
  const float* x     = (const float*)d_in[0];
  const int*   mask  = (const int*)  d_in[1];
  const float* Wq    = (const float*)d_in[2];
  const float* bq    = (const float*)d_in[3];
  const float* Wk    = (const float*)d_in[4];
  const float* bk    = (const float*)d_in[5];
  const float* Wv    = (const float*)d_in[6];
  const float* bv    = (const float*)d_in[7];
  const float* Wo    = (const float*)d_in[8];
  const float* bo    = (const float*)d_in[9];
  const float* pe    = (const float*)d_in[10];
  const float* alpha = (const float*)d_in[11];
  // beta (d_in[12]) is softmax-invariant (uniform per row) -> unused

  char* ws = (char*)d_ws;
  _Float16* x16 = (_Float16*)(ws + OFF_X16);
  _Float16* wq6 = (_Float16*)(ws + OFF_WQ);
  _Float16* wk6 = (_Float16*)(ws + OFF_WK);
  _Float16* wv6 = (_Float16*)(ws + OFF_WV);
  _Float16* wo6 = (_Float16*)(ws + OFF_WO);
  _Float16* Qa  = (_Float16*)(ws + OFF_QA);
  _Float16* Ka  = (_Float16*)(ws + OFF_KA);
  _Float16* Vt  = (_Float16*)(ws + OFF_VT);
  _Float16* AO  = (_Float16*)(ws + OFF_AO);
  float* out = (float*)d_out;

  cvt_all<<<4096, 256, 0, stream>>>(x, Wq, Wk, Wv, Wo, x16);
  fill_pe<<<2048, 256, 0, stream>>>(pe, alpha, Qa, Ka);
  gemm_nt<0><<<dim3(24, 32), 256, 0, stream>>>(x16, wq6, wk6, wv6, bq, bk, bv,
                                               Qa, Ka, Vt, nullptr);
  flash_attn<<<512, 512, 0, stream>>>(Qa, Ka, Vt, mask, AO);
  gemm_nt<1><<<dim3(8, 32), 256, 0, stream>>>(AO, wo6, nullptr, nullptr, bo,
                                              nullptr, nullptr, nullptr, nullptr,
                                              nullptr, out);
}

// Round 9
// 149.371 us; speedup vs baseline: 1.6426x; 1.0804x over previous
//
#include <hip/hip_runtime.h>

// ---------------- problem constants ----------------
#define BATCH 2
#define SEQ   2048
#define NH    16
#define DH    64
#define DA    128          // augmented head dim (content 64 + pos 64)
#define DM    1024
#define MTOT  (BATCH*SEQ)  // 4096

typedef _Float16 f16x8 __attribute__((ext_vector_type(8)));
typedef _Float16 f16x4 __attribute__((ext_vector_type(4)));
typedef float    f32x4 __attribute__((ext_vector_type(4)));
typedef float    f32x16 __attribute__((ext_vector_type(16)));

#define LOG2E 1.44269504088896340736f

// workspace offsets (bytes)
#define OFF_X16 0u
#define OFF_WQ  8388608u
#define OFF_WK  10485760u
#define OFF_WV  12582912u
#define OFF_WO  14680064u
#define OFF_QA  16777216u
#define OFF_KA  33554432u
#define OFF_VT  50331648u
#define OFF_AO  58720256u
// total 67108864 (64 MB)

__device__ __forceinline__ void gload_lds16(const _Float16* g, _Float16* l) {
  __builtin_amdgcn_global_load_lds(
      (const __attribute__((address_space(1))) unsigned int*)g,
      (__attribute__((address_space(3))) unsigned int*)l, 16, 0, 0);
}

__device__ __forceinline__ float fexp2(float x) {
  float r;
  asm("v_exp_f32 %0, %1" : "=v"(r) : "v"(x));
  return r;
}

__device__ __forceinline__ unsigned pk2(float a, float b) {
  auto v = __builtin_amdgcn_cvt_pkrtz(a, b);   // __fp16 ext_vector(2)
  return *(unsigned*)&v;
}

// ---------------- fp32 -> fp16 conversion (x + 4 weights) ----------------
__global__ __launch_bounds__(256) void cvt_all(
    const float* __restrict__ x,  const float* __restrict__ wq,
    const float* __restrict__ wk, const float* __restrict__ wv,
    const float* __restrict__ wo, _Float16* __restrict__ dst)
{
  int i = blockIdx.x * 256 + threadIdx.x;   // each thread: 8 floats
  const float* src;
  if (i < 524288) {
    src = x + (size_t)i * 8;
  } else {
    int j = i - 524288;
    int wi = j >> 17;                        // 131072 threads per weight
    const float* w = (wi == 0) ? wq : ((wi == 1) ? wk : ((wi == 2) ? wv : wo));
    src = w + (size_t)(j & 131071) * 8;
  }
  float4 a = ((const float4*)src)[0];
  float4 c = ((const float4*)src)[1];
  f16x8 hv;
  hv[0]=(_Float16)a.x; hv[1]=(_Float16)a.y; hv[2]=(_Float16)a.z; hv[3]=(_Float16)a.w;
  hv[4]=(_Float16)c.x; hv[5]=(_Float16)c.y; hv[6]=(_Float16)c.z; hv[7]=(_Float16)c.w;
  *(f16x8*)(dst + (size_t)i * 8) = hv;
}

// ---------------- fill positional halves of Qa/Ka (8-wide vectorized) -------
// Qa[b,h,s,64+d] = alpha[h]*LOG2E*pe[s,d] ; Ka[b,h,s,64+d] = pe[s,d]
__global__ __launch_bounds__(256) void fill_pe(
    const float* __restrict__ pe, const float* __restrict__ alpha,
    _Float16* __restrict__ Qa, _Float16* __restrict__ Ka)
{
  int idx = blockIdx.x * 256 + threadIdx.x;   // B*H*S*8 = 2^19 threads
  int c8 = idx & 7;
  int s  = (idx >> 3) & 2047;
  int h  = (idx >> 14) & 15;
  int b  = idx >> 18;
  const float4* p4 = (const float4*)(pe + s * 64 + c8 * 8);
  float4 a = p4[0], c = p4[1];
  float al = alpha[h] * LOG2E;
  f16x8 hk, hq;
  hk[0]=(_Float16)a.x; hk[1]=(_Float16)a.y; hk[2]=(_Float16)a.z; hk[3]=(_Float16)a.w;
  hk[4]=(_Float16)c.x; hk[5]=(_Float16)c.y; hk[6]=(_Float16)c.z; hk[7]=(_Float16)c.w;
  hq[0]=(_Float16)(al*a.x); hq[1]=(_Float16)(al*a.y); hq[2]=(_Float16)(al*a.z); hq[3]=(_Float16)(al*a.w);
  hq[4]=(_Float16)(al*c.x); hq[5]=(_Float16)(al*c.y); hq[6]=(_Float16)(al*c.z); hq[7]=(_Float16)(al*c.w);
  size_t o = ((size_t)((b * NH + h) * SEQ + s)) * DA + 64 + c8 * 8;
  *(f16x8*)&Qa[o] = hq;
  *(f16x8*)&Ka[o] = hk;
}

// ---------------- NT GEMM: C(M x N) = A(M x K) * W(N x K)^T ----------------
template<int MODE>
__global__ __launch_bounds__(256) void gemm_nt(
    const _Float16* __restrict__ A,
    const _Float16* __restrict__ W0, const _Float16* __restrict__ W1,
    const _Float16* __restrict__ W2,
    const float* __restrict__ b0, const float* __restrict__ b1,
    const float* __restrict__ b2,
    _Float16* __restrict__ Qa, _Float16* __restrict__ Ka,
    _Float16* __restrict__ Vt, float* __restrict__ Out)
{
  __shared__ _Float16 As[128 * 64];
  __shared__ _Float16 Bs[128 * 64];
  const int tid = threadIdx.x;
  const int w = tid >> 6, lane = tid & 63;
  const int g = lane >> 4, l16 = lane & 15;
  const int wm = w >> 1, wn = w & 1;

  int nb_all = blockIdx.x;
  int mblk = blockIdx.y;
  const _Float16* Bp; const float* biasp;
  int which = 0, nblk = nb_all;
  if (MODE == 0) {
    which = nb_all >> 3; nblk = nb_all & 7;
    Bp = (which == 0) ? W0 : ((which == 1) ? W1 : W2);
    biasp = (which == 0) ? b0 : ((which == 1) ? b1 : b2);
  } else {
    Bp = W0; biasp = b0;
  }

  f32x4 zero4 = {0.f, 0.f, 0.f, 0.f};
  f32x4 acc[4][4];
  #pragma unroll
  for (int mb = 0; mb < 4; ++mb)
    #pragma unroll
    for (int nb = 0; nb < 4; ++nb) acc[mb][nb] = zero4;

  const _Float16* Abase = A  + (size_t)mblk * 128 * DM;
  const _Float16* Bbase = Bp + (size_t)nblk * 128 * DM;

  for (int kt = 0; kt < DM / 64; ++kt) {
    __syncthreads();
    #pragma unroll
    for (int ii = 0; ii < 4; ++ii) {
      int i = w * 4 + ii;
      int rt = i * 8 + (lane >> 3);
      int cg = (lane & 7) ^ (rt & 7);
      gload_lds16(Abase + (size_t)rt * DM + kt * 64 + cg * 8, &As[i * 512]);
    }
    #pragma unroll
    for (int ii = 0; ii < 4; ++ii) {
      int i = w * 4 + ii;
      int rt = i * 8 + (lane >> 3);
      int cg = (lane & 7) ^ (rt & 7);
      gload_lds16(Bbase + (size_t)rt * DM + kt * 64 + cg * 8, &Bs[i * 512]);
    }
    __syncthreads();
    #pragma unroll
    for (int ks = 0; ks < 2; ++ks) {
      f16x8 av[4], bv[4];
      #pragma unroll
      for (int mb = 0; mb < 4; ++mb) {
        int rt = wm * 64 + mb * 16 + l16;
        av[mb] = *(const f16x8*)&As[rt * 64 + (((ks * 4 + g) ^ (rt & 7)) * 8)];
      }
      #pragma unroll
      for (int nb = 0; nb < 4; ++nb) {
        int rt = wn * 64 + nb * 16 + l16;
        bv[nb] = *(const f16x8*)&Bs[rt * 64 + (((ks * 4 + g) ^ (rt & 7)) * 8)];
      }
      #pragma unroll
      for (int mb = 0; mb < 4; ++mb)
        #pragma unroll
        for (int nb = 0; nb < 4; ++nb)
          acc[mb][nb] = __builtin_amdgcn_mfma_f32_16x16x32_f16(
              av[mb], bv[nb], acc[mb][nb], 0, 0, 0);
    }
  }

  // epilogue
  #pragma unroll
  for (int nb = 0; nb < 4; ++nb) {
    int n = nblk * 128 + wn * 64 + nb * 16 + l16;
    float bias = biasp[n];
    #pragma unroll
    for (int mb = 0; mb < 4; ++mb) {
      int m0 = mblk * 128 + wm * 64 + mb * 16 + g * 4;
      if (MODE == 0) {
        int hh = n >> 6, dd = n & 63;
        if (which == 2) {                    // V: write transposed Vt[bh,d,s]
          int bb = m0 >> 11, ss = m0 & 2047;
          f16x4 hv;
          #pragma unroll
          for (int r = 0; r < 4; ++r) hv[r] = (_Float16)(acc[mb][nb][r] + bias);
          *(f16x4*)&Vt[((size_t)((bb * NH + hh) * DH + dd)) * SEQ + ss] = hv;
        } else {
          #pragma unroll
          for (int r = 0; r < 4; ++r) {
            int m = m0 + r; int bb = m >> 11, ss = m & 2047;
            size_t o = ((size_t)((bb * NH + hh) * SEQ + ss)) * DA + dd;
            if (which == 0) Qa[o] = (_Float16)((acc[mb][nb][r] + bias) * (0.125f * LOG2E));
            else            Ka[o] = (_Float16)(acc[mb][nb][r] + bias);
          }
        }
      } else {
        #pragma unroll
        for (int r = 0; r < 4; ++r)
          Out[(size_t)(m0 + r) * DM + n] = acc[mb][nb][r] + bias;
      }
    }
  }
}

// ---------------- flash attention (32x32 MFMA, P in-register) --------------
// 512 blocks (XCD-pinned); 4 waves x 32 q-rows. Swapped QK^T (S^T = K Q^T),
// O^T = Vt P^T -> q = lane&31 everywhere, rescale lane-uniform.
// P relayout S^T->P^T-fragment via v_permlane32_swap (no P LDS).
// LDS 48KB -> 3 blocks/CU. Counted vmcnt(6) dbuf staging.
__global__ __launch_bounds__(256, 3) void flash_attn(
    const _Float16* __restrict__ Qa, const _Float16* __restrict__ Ka,
    const _Float16* __restrict__ Vt, const int* __restrict__ mask,
    _Float16* __restrict__ AO)
{
  __shared__ _Float16 Ks[2][64 * 128];  // 2 x 16KB  [key][Da] swizzled
  __shared__ _Float16 Vs[2][64 * 64];   // 2 x 8KB   [d][key] swizzled
  const int tid = threadIdx.x;
  const int w = tid >> 6, lane = tid & 63;
  const int l32 = lane & 31, hi = lane >> 5;

  int bid = blockIdx.x;                  // 512 blocks: bid&7 -> XCD
  int work = (bid & 7) * 64 + (bid >> 3);
  const int qt = work & 15;              // 16 q-tiles of 128
  const int bh = work >> 4;              // 4 bh per XCD -> K/V L2-resident
  const int h = bh & 15, b = bh >> 4;

  // Q as B-operand: col=q=l32, k-chunk hi -> Q[q][c16*16 + hi*8 + j]
  const _Float16* qbase = Qa + ((size_t)(bh * SEQ) + qt * 128 + w * 32) * DA;
  f16x8 qf[8];
  #pragma unroll
  for (int c16 = 0; c16 < 8; ++c16)
    qf[c16] = *(const f16x8*)&qbase[l32 * DA + c16 * 16 + hi * 8];

  f32x16 acco[2];                        // O^T: d=(reg&3)+8*(reg>>2)+4*hi+32*db, q=l32
  #pragma unroll
  for (int db = 0; db < 2; ++db)
    #pragma unroll
    for (int r = 0; r < 16; ++r) acco[db][r] = 0.f;
  float mrun = -3.0e38f, lrun = 0.f;

  const _Float16* kbase = Ka + (size_t)bh * SEQ * DA;
  const _Float16* vbase = Vt + (size_t)bh * DH * SEQ;
  const int* mbase = mask + b * SEQ;

  // wave-uniform mask precheck (all-ones in practice)
  int allm = 1;
  #pragma unroll 8
  for (int t = 0; t < SEQ / 64; ++t) allm &= (mbase[t * 64 + lane] != 0);
  const bool maskclean = __all(allm);

  auto STAGE = [&](int buf, int kt) {
    #pragma unroll
    for (int ii = 0; ii < 4; ++ii) {          // K: 1024 16B-chunks / 256 thr
      int i = ii * 256 + tid;
      int rt = i >> 4, c = i & 15;
      int cg = c ^ (rt & 7);
      gload_lds16(kbase + (size_t)(kt * 64 + rt) * DA + cg * 8, &Ks[buf][i * 8]);
    }
    #pragma unroll
    for (int ii = 0; ii < 2; ++ii) {          // V: 512 chunks / 256 thr
      int i = ii * 256 + tid;
      int rt = i >> 3, c = i & 7;
      int cg = c ^ (rt & 7);
      gload_lds16(vbase + (size_t)rt * SEQ + kt * 64 + cg * 8, &Vs[buf][i * 8]);
    }
  };

  STAGE(0, 0);
  int cur = 0;
  for (int kt = 0; kt < SEQ / 64; ++kt) {
    asm volatile("s_waitcnt lgkmcnt(0)" ::: "memory");
    __builtin_amdgcn_s_barrier();
    asm volatile("" ::: "memory");
    if (kt + 1 < SEQ / 64) {
      STAGE(cur ^ 1, kt + 1);                 // prefetch next tile
      asm volatile("s_waitcnt vmcnt(6)" ::: "memory");  // tile kt landed
    } else {
      asm volatile("s_waitcnt vmcnt(0)" ::: "memory");
    }
    __builtin_amdgcn_s_barrier();
    asm volatile("" ::: "memory");

    // QK^T: S^T[key][q], 2 key-blocks of 32
    f32x16 sfr[2];
    __builtin_amdgcn_s_setprio(1);
    #pragma unroll
    for (int kb = 0; kb < 2; ++kb) {
      f32x16 s;
      #pragma unroll
      for (int r = 0; r < 16; ++r) s[r] = 0.f;
      int rt = kb * 32 + l32;
      #pragma unroll
      for (int c16 = 0; c16 < 8; ++c16) {
        int ch = (2 * c16 + hi) ^ (rt & 7);
        f16x8 kf = *(const f16x8*)&Ks[cur][rt * 128 + ch * 8];
        s = __builtin_amdgcn_mfma_f32_32x32x16_f16(kf, qf[c16], s, 0, 0, 0);
      }
      sfr[kb] = s;
    }
    __builtin_amdgcn_s_setprio(0);

    // rare slow path: mask pre-max (never taken for all-ones mask)
    if (!maskclean) {
      #pragma unroll
      for (int kb = 0; kb < 2; ++kb)
        #pragma unroll
        for (int r = 0; r < 16; ++r) {
          int key = kt * 64 + kb * 32 + (r & 3) + 8 * (r >> 2) + 4 * hi;
          if (mbase[key] == 0) sfr[kb][r] = -3.0e38f;
        }
    }

    // per-lane row softmax for q=l32 (lane pair (l32, l32+32) splits keys)
    float mx = sfr[0][0];
    #pragma unroll
    for (int kb = 0; kb < 2; ++kb)
      #pragma unroll
      for (int r = 0; r < 16; ++r) mx = fmaxf(mx, sfr[kb][r]);
    mx = fmaxf(mx, __shfl_xor(mx, 32));

    const bool rescale = !__all(mx <= mrun + 8.0f);   // defer-max THR=8
    float mnew = mrun, scale = 1.0f;
    if (rescale) {
      mnew = fmaxf(mrun, mx);
      scale = fexp2(mrun - mnew);
    }
    float rsum = 0.f;
    unsigned pk[2][4][2];                 // [kb][quad rq][u32 pair]
    #pragma unroll
    for (int kb = 0; kb < 2; ++kb)
      #pragma unroll
      for (int rq = 0; rq < 4; ++rq) {
        float p0 = fexp2(sfr[kb][rq * 4 + 0] - mnew);
        float p1 = fexp2(sfr[kb][rq * 4 + 1] - mnew);
        float p2 = fexp2(sfr[kb][rq * 4 + 2] - mnew);
        float p3 = fexp2(sfr[kb][rq * 4 + 3] - mnew);
        rsum += (p0 + p1) + (p2 + p3);
        pk[kb][rq][0] = pk2(p0, p1);
        pk[kb][rq][1] = pk2(p2, p3);
      }
    rsum += __shfl_xor(rsum, 32);
    if (rescale) {
      lrun = lrun * scale + rsum;
      mrun = mnew;
      #pragma unroll
      for (int db = 0; db < 2; ++db)
        #pragma unroll
        for (int r = 0; r < 16; ++r) acco[db][r] *= scale;
    } else {
      lrun += rsum;
    }

    // PV: O^T += Vt * P^T; pf built per 16-key chunk via permlane32_swap
    __builtin_amdgcn_s_setprio(1);
    #pragma unroll
    for (int c = 0; c < 4; ++c) {         // k-chunk of 16 keys
      const int kb = c >> 1, c2 = c & 1;
      unsigned X0 = pk[kb][2 * c2][0],     X1 = pk[kb][2 * c2][1];
      unsigned Y0 = pk[kb][2 * c2 + 1][0], Y1 = pk[kb][2 * c2 + 1][1];
      // swap upper lanes of X with lower lanes of Y:
      // X' = [X.lo | Y.lo(partner)], Y' = [X.hi(partner) | Y.hi]
      asm("v_permlane32_swap_b32 %0, %1" : "+v"(X0), "+v"(Y0));
      asm("v_permlane32_swap_b32 %0, %1" : "+v"(X1), "+v"(Y1));
      union { unsigned u[4]; f16x8 v; } pu;
      pu.u[0] = X0; pu.u[1] = X1; pu.u[2] = Y0; pu.u[3] = Y1;
      #pragma unroll
      for (int db = 0; db < 2; ++db) {
        int row = db * 32 + l32;
        int ch = (2 * c + hi) ^ (row & 7);
        f16x8 vf = *(const f16x8*)&Vs[cur][row * 64 + ch * 8];
        acco[db] = __builtin_amdgcn_mfma_f32_32x32x16_f16(vf, pu.v, acco[db], 0, 0, 0);
      }
    }
    __builtin_amdgcn_s_setprio(0);
    cur ^= 1;
  }

  // epilogue: AO[b, sg, h*64+d] = O^T[d][q]/l ; d = db*32 + rq*8 + hi*4 + j
  float inv = 1.0f / lrun;
  int sg = qt * 128 + w * 32 + l32;
  _Float16* aobase = AO + ((size_t)(b * SEQ + sg)) * DM + h * DH;
  #pragma unroll
  for (int db = 0; db < 2; ++db)
    #pragma unroll
    for (int rq = 0; rq < 4; ++rq) {
      f16x4 o;
      #pragma unroll
      for (int j = 0; j < 4; ++j) o[j] = (_Float16)(acco[db][rq * 4 + j] * inv);
      *(f16x4*)&aobase[db * 32 + rq * 8 + hi * 4] = o;
    }
}

// ---------------- launch ----------------
extern "C" void kernel_launch(void* const* d_in, const int* in_sizes, int n_in,
                              void* d_out, int out_size, void* d_ws, size_t ws_size,
                              hipStream_t stream) {
  const float* x     = (const float*)d_in[0];
  const int*   mask  = (const int*)  d_in[1];
  const float* Wq    = (const float*)d_in[2];
  const float* bq    = (const float*)d_in[3];
  const float* Wk    = (const float*)d_in[4];
  const float* bk    = (const float*)d_in[5];
  const float* Wv    = (const float*)d_in[6];
  const float* bv    = (const float*)d_in[7];
  const float* Wo    = (const float*)d_in[8];
  const float* bo    = (const float*)d_in[9];
  const float* pe    = (const float*)d_in[10];
  const float* alpha = (const float*)d_in[11];
  // beta (d_in[12]) is softmax-invariant (uniform per row) -> unused

  char* ws = (char*)d_ws;
  _Float16* x16 = (_Float16*)(ws + OFF_X16);
  _Float16* wq6 = (_Float16*)(ws + OFF_WQ);
  _Float16* wk6 = (_Float16*)(ws + OFF_WK);
  _Float16* wv6 = (_Float16*)(ws + OFF_WV);
  _Float16* wo6 = (_Float16*)(ws + OFF_WO);
  _Float16* Qa  = (_Float16*)(ws + OFF_QA);
  _Float16* Ka  = (_Float16*)(ws + OFF_KA);
  _Float16* Vt  = (_Float16*)(ws + OFF_VT);
  _Float16* AO  = (_Float16*)(ws + OFF_AO);
  float* out = (float*)d_out;

  cvt_all<<<4096, 256, 0, stream>>>(x, Wq, Wk, Wv, Wo, x16);
  fill_pe<<<2048, 256, 0, stream>>>(pe, alpha, Qa, Ka);
  gemm_nt<0><<<dim3(24, 32), 256, 0, stream>>>(x16, wq6, wk6, wv6, bq, bk, bv,
                                               Qa, Ka, Vt, nullptr);
  flash_attn<<<512, 256, 0, stream>>>(Qa, Ka, Vt, mask, AO);
  gemm_nt<1><<<dim3(8, 32), 256, 0, stream>>>(AO, wo6, nullptr, nullptr, bo,
                                              nullptr, nullptr, nullptr, nullptr,
                                              nullptr, out);
}